// Round 3
// baseline (796.872 us; speedup 1.0000x reference)
//
#include <hip/hip_runtime.h>
#include <hip/hip_cooperative_groups.h>
#include <math.h>

namespace cg = cooperative_groups;

#define Bc 32
#define Sc 2048
#define Dc 1024
#define Mc 1024
#define LNEPS 1e-5f
#define NBLK 512
#define SCv (1.f/67108864.f)   // 1/(B*S*M)

struct Params {
    const float *X, *mem, *mom, *Wk, *bk, *Wv, *bv, *memW, *memb, *lng, *lnb,
                *Wf, *bf, *Wu, *bu, *eta, *theta;
    float *out, *ws;
};

__device__ __forceinline__ void dreduce(float& a, float& b, float* sm) {
#pragma unroll
    for (int o = 32; o; o >>= 1) { a += __shfl_xor(a, o); b += __shfl_xor(b, o); }
    int w = threadIdx.x >> 6;
    if ((threadIdx.x & 63) == 0) { sm[w] = a; sm[4 + w] = b; }
    __syncthreads();
    a = sm[0] + sm[1] + sm[2] + sm[3];
    b = sm[4] + sm[5] + sm[6] + sm[7];
    __syncthreads();
}

// A-tile loader: Atile[8][256] = A[b0..b0+7][k0..k0+255], A is [32,1024]
__device__ __forceinline__ void load_A_global(float* Atile, const float* A, int b0, int k0) {
    for (int i = threadIdx.x; i < 2048; i += 256) {
        int r = i >> 8, c = i & 255;
        Atile[i] = A[(size_t)(b0 + r) * 1024 + k0 + c];
    }
}

// split-K NT inner: Atile[8][256] (LDS) x W[1024,1024] -> partials P[ks][b][n]
__device__ __forceinline__ void nt_inner(const float* Atile, const float* W, int k0, int n0,
                                         float* P, int ks, int b0) {
    int n = n0 + (threadIdx.x & 63), bl = threadIdx.x >> 6;
    const float* a0 = Atile + bl * 256;
    const float* a1 = Atile + (bl + 4) * 256;
    const float* Wp = W + (size_t)k0 * 1024 + n;
    float acc0 = 0.f, acc1 = 0.f;
#pragma unroll 8
    for (int k = 0; k < 256; ++k) {
        float wv = Wp[(size_t)k * 1024];
        acc0 = fmaf(a0[k], wv, acc0);
        acc1 = fmaf(a1[k], wv, acc1);
    }
    size_t base = (size_t)ks * Bc * 1024 + n;
    P[base + (size_t)(b0 + bl) * 1024] = acc0;
    P[base + (size_t)(b0 + bl + 4) * 1024] = acc1;
}

// build h-tile = SiLU(LN(bias + sum4 P)) rows b0..b0+7, cols k0..k0+255 into shm[0..2047]
__device__ __forceinline__ void build_h_tile(float* shm, const float* P, const float* bias,
                                             const float* g, const float* be, int b0, int k0) {
    float* Atile = shm;
    float* stats = shm + 2048;   // mean[8], rstd[8]
    float* red = shm + 2064;
    for (int r = 0; r < 8; ++r) {
        int b = b0 + r;
        float s = 0.f, sq = 0.f;
        for (int m = threadIdx.x; m < 1024; m += 256) {
            float z = bias[m] + P[(size_t)b * 1024 + m] + P[(size_t)(Bc + b) * 1024 + m]
                    + P[(size_t)(2 * Bc + b) * 1024 + m] + P[(size_t)(3 * Bc + b) * 1024 + m];
            if ((unsigned)(m - k0) < 256u) Atile[r * 256 + (m - k0)] = z;
            s += z; sq += z * z;
        }
        dreduce(s, sq, red);
        if (threadIdx.x == 0) {
            float mean = s * (1.f / 1024.f);
            float var = sq * (1.f / 1024.f) - mean * mean;
            stats[r] = mean; stats[8 + r] = rsqrtf(var + LNEPS);
        }
    }
    __syncthreads();
    for (int i = threadIdx.x; i < 2048; i += 256) {
        int r = i >> 8, c = i & 255, m = k0 + c;
        float xh = (Atile[i] - stats[r]) * stats[8 + r];
        float y = fmaf(xh, g[m], be[m]);
        float sg = 1.f / (1.f + __expf(-y));
        Atile[i] = y * sg;
    }
    __syncthreads();
}

// LN-backward (full-row recompute) + gemm-T slice dot.
// dz = bwd(gv, z) where z = bias + sum4 Pz; gv = sum4 Pgrad (mode1: gv=SC*(gv+bk*rs[b]))
// out: Pout[mc][b][d] = sum_{m in chunk mc} dz[b,m]*W[d*1024+m]
__device__ __forceinline__ void lnbwd_gemmT(float* shm, const float* Pz, const float* bias,
                                            const float* g, const float* be, const float* Pgrad,
                                            int mode, const float* bk, const float* rsvp,
                                            const float* W, float* Pout, int bid, int tid) {
    int dc = bid & 3, b = (bid >> 2) & 31, mc = bid >> 7, m0 = mc * 256;
    float* zrow = shm;           // 1024
    float* arow = shm + 1024;    // 1024
    float* Asl = shm + 2048;     // 256
    float* red = shm + 2304;     // 8
    float s = 0.f, sq = 0.f;
    for (int m = tid; m < 1024; m += 256) {
        float z = bias[m] + Pz[(size_t)b * 1024 + m] + Pz[(size_t)(32 + b) * 1024 + m]
                + Pz[(size_t)(64 + b) * 1024 + m] + Pz[(size_t)(96 + b) * 1024 + m];
        zrow[m] = z; s += z; sq += z * z;
    }
    dreduce(s, sq, red);
    float mean = s * (1.f / 1024.f);
    float rstd = rsqrtf(sq * (1.f / 1024.f) - mean * mean + LNEPS);
    float rsb = mode ? rsvp[b] : 0.f;
    float sa = 0.f, sax = 0.f;
    for (int m = tid; m < 1024; m += 256) {
        float gv = Pgrad[(size_t)b * 1024 + m] + Pgrad[(size_t)(32 + b) * 1024 + m]
                 + Pgrad[(size_t)(64 + b) * 1024 + m] + Pgrad[(size_t)(96 + b) * 1024 + m];
        if (mode) gv = SCv * (gv + bk[m] * rsb);
        float xh = (zrow[m] - mean) * rstd;
        float y = fmaf(xh, g[m], be[m]);
        float sg = 1.f / (1.f + __expf(-y));
        float dsilu = sg * (1.f + y * (1.f - sg));
        float a = gv * dsilu * g[m];
        arow[m] = a; sa += a; sax += a * xh;
    }
    dreduce(sa, sax, red);
    float ma = sa * (1.f / 1024.f), mx = sax * (1.f / 1024.f);
    {
        int m = m0 + tid;
        float xh = (zrow[m] - mean) * rstd;
        Asl[tid] = rstd * (arow[m] - ma - xh * mx);
    }
    __syncthreads();
    int d = dc * 256 + tid;
    const float4* Wr = (const float4*)(W + (size_t)d * 1024 + m0);
    const float4* Ar = (const float4*)Asl;
    float acc = 0.f;
#pragma unroll 8
    for (int i = 0; i < 64; ++i) {
        float4 w4 = Wr[i], a4 = Ar[i];
        acc += w4.x * a4.x + w4.y * a4.y + w4.z * a4.z + w4.w * a4.w;
    }
    Pout[(size_t)(mc * 32 + b) * 1024 + d] = acc;
}

__global__ __launch_bounds__(256, 2) void mega(Params p) {
    __shared__ float shm[4352];
    const int bid = blockIdx.x, tid = threadIdx.x;
    cg::grid_group grid = cg::this_grid();
    const size_t BM = (size_t)Bc * Mc;
    float* ws = p.ws;
    float* P1a   = ws;             // 4*BM  mem@W0 partials
    float* P2a   = ws + 4 * BM;    // h1@W1 partials
    float* wpart = ws + 8 * BM;
    float* Pg    = ws + 12 * BM;
    float* Pfp   = ws + 16 * BM;
    float* Pup   = ws + 20 * BM;
    float* Pfm   = ws + 24 * BM;
    float* Pum   = ws + 28 * BM;
    float* ghp   = ws + 32 * BM;
    float* surp  = ws + 36 * BM;
    float* P3a   = ws + 40 * BM;   // nmem@W0 partials
    float* P4a   = ws + 44 * BM;   // hp@W1 partials
    float* tbuf  = ws + 48 * BM;
    float* pooled= ws + 49 * BM;
    float* wv_row= ws + 50 * BM;          // 1024
    float* bvsum = wv_row + 1024;         // 1
    float* cbpart= bvsum + 1;             // 128
    float* rsv   = cbpart + 128;          // 32
    float* rs_part = rsv + 32;            // 1024
    float* t_part = ws + 52 * BM;         // 32*BM
    float* p_part = ws + 84 * BM;         // 32*BM

    const float* W0 = p.memW;
    const float* W1 = p.memW + (size_t)Mc * Mc;
    const float *memb0 = p.memb, *memb1 = p.memb + 1024;
    const float *lng0 = p.lng, *lng1 = p.lng + 1024;
    const float *lnb0 = p.lnb, *lnb1 = p.lnb + 1024;

    // ---- P0: wv_row/bvsum prep + mem@{W0, Wf_bot, Wu_bot} split-K partials ----
    {
        float s1 = 0.f, s2 = 0.f;
        for (int m = tid; m < 1024; m += 256) {
            s1 += p.Wv[(size_t)bid * 1024 + m];
            s2 += p.Wv[(size_t)(bid + 512) * 1024 + m];
        }
        dreduce(s1, s2, shm + 2064);
        if (tid == 0) { wv_row[bid] = s1; wv_row[bid + 512] = s2; }
        if (bid == 0) {
            float v = 0.f, d2 = 0.f;
            for (int m = tid; m < 1024; m += 256) v += p.bv[m];
            dreduce(v, d2, shm + 2064);
            if (tid == 0) *bvsum = v;
        }
        if (bid < 256) {
            int n0 = (bid & 15) * 64, b0 = ((bid >> 4) & 3) * 8, ks = bid >> 6, k0 = ks * 256;
            load_A_global(shm, p.mem, b0, k0);
            __syncthreads();
            nt_inner(shm, W0, k0, n0, P1a, ks, b0);
            nt_inner(shm, p.Wf + (size_t)1024 * 1024, k0, n0, Pfm, ks, b0);
            nt_inner(shm, p.Wu + (size_t)1024 * 1024, k0, n0, Pum, ks, b0);
        }
    }
    grid.sync();

    // ---- P1: GEMM2 (h1@W1) with LN1 recompute ----
    if (bid < 256) {
        int n0 = (bid & 15) * 64, b0 = ((bid >> 4) & 3) * 8, ks = bid >> 6, k0 = ks * 256;
        build_h_tile(shm, P1a, memb0, lng0, lnb0, b0, k0);
        nt_inner(shm, W1, k0, n0, P2a, ks, b0);
    }
    grid.sync();

    // ---- P2: wpart = mo@Wk^T (LN2 recompute) + cbpart ----
    {
        int dc = bid & 3, b = (bid >> 2) & 31, mc = bid >> 7, m0 = mc * 256;
        float* Asl = shm; float* red = shm + 264;
        float s = 0.f, sq = 0.f;
        for (int m = tid; m < 1024; m += 256) {
            float z = memb1[m] + P2a[(size_t)b * 1024 + m] + P2a[(size_t)(32 + b) * 1024 + m]
                    + P2a[(size_t)(64 + b) * 1024 + m] + P2a[(size_t)(96 + b) * 1024 + m];
            if ((unsigned)(m - m0) < 256u) Asl[m - m0] = z;
            s += z; sq += z * z;
        }
        dreduce(s, sq, red);
        float mean = s * (1.f / 1024.f);
        float rstd = rsqrtf(sq * (1.f / 1024.f) - mean * mean + LNEPS);
        {
            int m = m0 + tid;
            float xh = (Asl[tid] - mean) * rstd;
            float y = fmaf(xh, lng1[m], lnb1[m]);
            float sg = 1.f / (1.f + __expf(-y));
            Asl[tid] = y * sg;
        }
        __syncthreads();
        if (dc == 0) {
            float c = p.bk[m0 + tid] * Asl[tid], d2 = 0.f;
            dreduce(c, d2, red);
            if (tid == 0) cbpart[mc * 32 + b] = c;
        }
        int d = dc * 256 + tid;
        const float4* Wr = (const float4*)(p.Wk + (size_t)d * 1024 + m0);
        const float4* Ar = (const float4*)Asl;
        float acc = 0.f;
#pragma unroll 8
        for (int i = 0; i < 64; ++i) {
            float4 w4 = Wr[i], a4 = Ar[i];
            acc += w4.x * a4.x + w4.y * a4.y + w4.z * a4.z + w4.w * a4.w;
        }
        wpart[(size_t)(mc * 32 + b) * 1024 + d] = acc;
    }
    grid.sync();

    // ---- P3: the one pass over X ----
    {
        int b = bid >> 4, blk = bid & 15;
        int lane = tid & 63, wv = tid >> 6;
        float* red = shm; float* rsum_s = shm + 4096;
        float4 wreg[4];
        const float4* wp4 = (const float4*)wpart;
        const float4* wr4 = (const float4*)wv_row;
#pragma unroll
        for (int j = 0; j < 4; ++j) {
            int d4 = lane + 64 * j;
            float4 s0 = wp4[((size_t)b) * 256 + d4];
            float4 s1 = wp4[((size_t)(32 + b)) * 256 + d4];
            float4 s2 = wp4[((size_t)(64 + b)) * 256 + d4];
            float4 s3 = wp4[((size_t)(96 + b)) * 256 + d4];
            float4 wr = wr4[d4];
            wreg[j].x = 1024.f * (s0.x + s1.x + s2.x + s3.x) - wr.x;
            wreg[j].y = 1024.f * (s0.y + s1.y + s2.y + s3.y) - wr.y;
            wreg[j].z = 1024.f * (s0.z + s1.z + s2.z + s3.z) - wr.z;
            wreg[j].w = 1024.f * (s0.w + s1.w + s2.w + s3.w) - wr.w;
        }
        float cbv = 1024.f * (cbpart[b] + cbpart[32 + b] + cbpart[64 + b] + cbpart[96 + b]) - *bvsum;
        for (int half = 0; half < 2; ++half) {
            int ch = blk * 2 + half;
            float4 tacc[4], pacc[4];
#pragma unroll
            for (int j = 0; j < 4; ++j) {
                tacc[j] = make_float4(0.f, 0.f, 0.f, 0.f);
                pacc[j] = make_float4(0.f, 0.f, 0.f, 0.f);
            }
            float rloc = 0.f;
            int s0r = ch * 64 + wv * 16;
#pragma unroll 2
            for (int i = 0; i < 16; ++i) {
                const float4* xr = (const float4*)(p.X + ((size_t)b * Sc + s0r + i) * Dc);
                float4 x[4]; float pp = 0.f;
#pragma unroll
                for (int j = 0; j < 4; ++j) {
                    x[j] = xr[lane + 64 * j];
                    pp += x[j].x * wreg[j].x + x[j].y * wreg[j].y + x[j].z * wreg[j].z + x[j].w * wreg[j].w;
                }
#pragma unroll
                for (int o = 32; o; o >>= 1) pp += __shfl_xor(pp, o);
                float r = pp + cbv;
                rloc += r;
#pragma unroll
                for (int j = 0; j < 4; ++j) {
                    tacc[j].x = fmaf(x[j].x, r, tacc[j].x);
                    tacc[j].y = fmaf(x[j].y, r, tacc[j].y);
                    tacc[j].z = fmaf(x[j].z, r, tacc[j].z);
                    tacc[j].w = fmaf(x[j].w, r, tacc[j].w);
                    pacc[j].x += x[j].x; pacc[j].y += x[j].y;
                    pacc[j].z += x[j].z; pacc[j].w += x[j].w;
                }
            }
            float4* redv = (float4*)red;
#pragma unroll
            for (int j = 0; j < 4; ++j) redv[wv * 256 + lane + 64 * j] = tacc[j];
            if (lane == 0) rsum_s[wv] = rloc;
            __syncthreads();
            size_t pb = ((size_t)b * 32 + ch) * 1024;
            for (int j = 0; j < 4; ++j) {
                int d = tid + 256 * j;
                t_part[pb + d] = red[d] + red[1024 + d] + red[2048 + d] + red[3072 + d];
            }
            if (tid == 0) rs_part[b * 32 + ch] = rsum_s[0] + rsum_s[1] + rsum_s[2] + rsum_s[3];
            __syncthreads();
#pragma unroll
            for (int j = 0; j < 4; ++j) redv[wv * 256 + lane + 64 * j] = pacc[j];
            __syncthreads();
            for (int j = 0; j < 4; ++j) {
                int d = tid + 256 * j;
                p_part[pb + d] = red[d] + red[1024 + d] + red[2048 + d] + red[3072 + d];
            }
            __syncthreads();
        }
    }
    grid.sync();

    // ---- P4: chunk reduce -> tbuf, pooled, rsv ----
    if (bid < 128) {
        int idx = bid * 256 + tid, b = idx >> 10, d = idx & 1023;
        float st = 0.f, sp = 0.f;
        size_t base = (size_t)b * 32 * 1024 + d;
        for (int ch = 0; ch < 32; ++ch) {
            st += t_part[base + (size_t)ch * 1024];
            sp += p_part[base + (size_t)ch * 1024];
        }
        tbuf[idx] = st;
        pooled[idx] = sp * (1.f / 2048.f);
        if (bid == 0 && tid < 32) {
            float s = 0.f;
            for (int ch = 0; ch < 32; ++ch) s += rs_part[tid * 32 + ch];
            rsv[tid] = s;
        }
    }
    grid.sync();

    // ---- P5: tbuf@Wk -> Pg ; pooled@{Wf_top,Wu_top} -> Pfp,Pup ----
    if (bid < 256) {
        int n0 = (bid & 15) * 64, b0 = ((bid >> 4) & 3) * 8, ks = bid >> 6, k0 = ks * 256;
        load_A_global(shm, tbuf, b0, k0);
        __syncthreads();
        nt_inner(shm, p.Wk, k0, n0, Pg, ks, b0);
    } else {
        int t = bid - 256;
        int n0 = (t & 15) * 64, b0 = ((t >> 4) & 3) * 8, ks = t >> 6, k0 = ks * 256;
        load_A_global(shm, pooled, b0, k0);
        __syncthreads();
        nt_inner(shm, p.Wf, k0, n0, Pfp, ks, b0);
        nt_inner(shm, p.Wu, k0, n0, Pup, ks, b0);
    }
    grid.sync();

    // ---- P6: ghp = dz1@W1^T with LN1-bwd recompute ----
    lnbwd_gemmT(shm, P2a, memb1, lng1, lnb1, Pg, 1, p.bk, rsv, W1, ghp, bid, tid);
    grid.sync();

    // ---- P7: surp = dz0@W0^T with LN0-bwd recompute ----
    lnbwd_gemmT(shm, P1a, memb0, lng0, lnb0, ghp, 0, nullptr, nullptr, W0, surp, bid, tid);
    grid.sync();

    // ---- P8: update recompute -> nmem tile -> GEMM3 (nmem@W0); write out[BM:2BM] ----
    if (bid < 256) {
        int n0idx = bid & 15, n0 = n0idx * 64, b0 = ((bid >> 4) & 3) * 8, ks = bid >> 6, k0 = ks * 256;
        float etav = p.eta[0], thv = p.theta[0];
        for (int i = tid; i < 2048; i += 256) {
            int r = i >> 8, c = i & 255, b = b0 + r, m = k0 + c;
            size_t o = (size_t)b * 1024 + m;
            float zf = p.bf[m], zu = p.bu[m], sv = 0.f;
#pragma unroll
            for (int s4 = 0; s4 < 4; ++s4) {
                size_t ob = (size_t)s4 * BM + o;
                zf += Pfm[ob] + Pfp[ob];
                zu += Pum[ob] + Pup[ob];
                sv += surp[ob];
            }
            float f = 1.f / (1.f + __expf(-zf));
            float u = 1.f / (1.f + __expf(-zu));
            float nm = (1.f - f) * p.mem[o] + u * (etav * p.mom[o] + thv * sv);
            shm[i] = nm;
            if (n0idx == 0) p.out[BM + o] = nm;
        }
        __syncthreads();
        nt_inner(shm, W0, k0, n0, P3a, ks, b0);
    }
    grid.sync();

    // ---- P9: GEMM4 (hp@W1) with LN3 recompute ----
    if (bid < 256) {
        int n0 = (bid & 15) * 64, b0 = ((bid >> 4) & 3) * 8, ks = bid >> 6, k0 = ks * 256;
        build_h_tile(shm, P3a, memb0, lng0, lnb0, b0, k0);
        nt_inner(shm, W1, k0, n0, P4a, ks, b0);
    }
    grid.sync();

    // ---- P10: final LN -> out[0:BM] ----
    if (bid < 32) {
        int b = bid;
        float zv[4]; float s = 0.f, sq = 0.f;
        for (int j = 0; j < 4; ++j) {
            int m = tid + 256 * j;
            float z = memb1[m] + P4a[(size_t)b * 1024 + m] + P4a[(size_t)(32 + b) * 1024 + m]
                    + P4a[(size_t)(64 + b) * 1024 + m] + P4a[(size_t)(96 + b) * 1024 + m];
            zv[j] = z; s += z; sq += z * z;
        }
        dreduce(s, sq, shm);
        float mean = s * (1.f / 1024.f);
        float rstd = rsqrtf(sq * (1.f / 1024.f) - mean * mean + LNEPS);
        for (int j = 0; j < 4; ++j) {
            int m = tid + 256 * j;
            float xh = (zv[j] - mean) * rstd;
            float y = fmaf(xh, lng1[m], lnb1[m]);
            float sg = 1.f / (1.f + __expf(-y));
            p.out[(size_t)b * 1024 + m] = y * sg;
        }
    }
}

extern "C" void kernel_launch(void* const* d_in, const int* in_sizes, int n_in,
                              void* d_out, int out_size, void* d_ws, size_t ws_size,
                              hipStream_t stream) {
    Params h;
    h.X    = (const float*)d_in[0];
    h.mem  = (const float*)d_in[1];
    h.mom  = (const float*)d_in[2];
    h.Wk   = (const float*)d_in[3];
    h.bk   = (const float*)d_in[4];
    h.Wv   = (const float*)d_in[5];
    h.bv   = (const float*)d_in[6];
    h.memW = (const float*)d_in[7];
    h.memb = (const float*)d_in[8];
    h.lng  = (const float*)d_in[9];
    h.lnb  = (const float*)d_in[10];
    h.Wf   = (const float*)d_in[11];
    h.bf   = (const float*)d_in[12];
    h.Wu   = (const float*)d_in[15];
    h.bu   = (const float*)d_in[16];
    h.eta  = (const float*)d_in[17];
    h.theta= (const float*)d_in[18];
    h.out  = (float*)d_out;
    h.ws   = (float*)d_ws;
    void* args[] = { (void*)&h };
    hipLaunchCooperativeKernel((const void*)mega, dim3(NBLK), dim3(256), args, 0, stream);
}

// Round 4
// 241.793 us; speedup vs baseline: 3.2957x; 3.2957x over previous
//
#include <hip/hip_runtime.h>
#include <math.h>

#define Bc 32
#define Sc 2048
#define Dc 1024
#define Mc 1024
#define LNEPS 1e-5f
#define SCv (1.f/67108864.f)   // 1/(B*S*M)

__device__ __forceinline__ void dreduce(float& a, float& b, float* sm) {
#pragma unroll
    for (int o = 32; o; o >>= 1) { a += __shfl_xor(a, o); b += __shfl_xor(b, o); }
    int w = threadIdx.x >> 6;
    if ((threadIdx.x & 63) == 0) { sm[w] = a; sm[4 + w] = b; }
    __syncthreads();
    a = sm[0] + sm[1] + sm[2] + sm[3];
    b = sm[4] + sm[5] + sm[6] + sm[7];
    __syncthreads();
}

__device__ __forceinline__ void load_A_global(float* Atile, const float* A, int b0, int k0) {
    for (int i = threadIdx.x; i < 2048; i += 256) {
        int r = i >> 8, c = i & 255;
        Atile[i] = A[(size_t)(b0 + r) * 1024 + k0 + c];
    }
}

// split-K NT inner: Atile[8][256] (LDS) x W[1024,1024] -> partials P[ks][b][n]
__device__ __forceinline__ void nt_inner(const float* Atile, const float* W, int k0, int n0,
                                         float* P, int ks, int b0) {
    int n = n0 + (threadIdx.x & 63), bl = threadIdx.x >> 6;
    const float* a0 = Atile + bl * 256;
    const float* a1 = Atile + (bl + 4) * 256;
    const float* Wp = W + (size_t)k0 * 1024 + n;
    float acc0 = 0.f, acc1 = 0.f;
#pragma unroll 8
    for (int k = 0; k < 256; ++k) {
        float wv = Wp[(size_t)k * 1024];
        acc0 = fmaf(a0[k], wv, acc0);
        acc1 = fmaf(a1[k], wv, acc1);
    }
    size_t base = (size_t)ks * Bc * 1024 + n;
    P[base + (size_t)(b0 + bl) * 1024] = acc0;
    P[base + (size_t)(b0 + bl + 4) * 1024] = acc1;
}

// h-tile = SiLU(LN(bias + sum4 P)) rows b0..b0+7, cols k0..k0+255 -> shm[0..2047]
__device__ __forceinline__ void build_h_tile(float* shm, const float* P, const float* bias,
                                             const float* g, const float* be, int b0, int k0) {
    float* Atile = shm;
    float* stats = shm + 2048;
    float* red = shm + 2064;
    for (int r = 0; r < 8; ++r) {
        int b = b0 + r;
        float s = 0.f, sq = 0.f;
        for (int m = threadIdx.x; m < 1024; m += 256) {
            float z = bias[m] + P[(size_t)b * 1024 + m] + P[(size_t)(Bc + b) * 1024 + m]
                    + P[(size_t)(2 * Bc + b) * 1024 + m] + P[(size_t)(3 * Bc + b) * 1024 + m];
            if ((unsigned)(m - k0) < 256u) Atile[r * 256 + (m - k0)] = z;
            s += z; sq += z * z;
        }
        dreduce(s, sq, red);
        if (threadIdx.x == 0) {
            float mean = s * (1.f / 1024.f);
            float var = sq * (1.f / 1024.f) - mean * mean;
            stats[r] = mean; stats[8 + r] = rsqrtf(var + LNEPS);
        }
    }
    __syncthreads();
    for (int i = threadIdx.x; i < 2048; i += 256) {
        int r = i >> 8, c = i & 255, m = k0 + c;
        float xh = (Atile[i] - stats[r]) * stats[8 + r];
        float y = fmaf(xh, g[m], be[m]);
        float sg = 1.f / (1.f + __expf(-y));
        Atile[i] = y * sg;
    }
    __syncthreads();
}

// K1: wv_row/bvsum prep (bid<256) + mem@{W0,Wf_bot,Wu_bot} partials. grid 1024
__global__ void k_front(const float* __restrict__ Wv, const float* __restrict__ bv,
                        const float* __restrict__ mem, const float* __restrict__ W0,
                        const float* __restrict__ Wfb, const float* __restrict__ Wub,
                        float* __restrict__ wv_row, float* __restrict__ bvsum,
                        float* __restrict__ P1a, float* __restrict__ Pfm, float* __restrict__ Pum) {
    __shared__ float shm[2080];
    int bid = blockIdx.x, tid = threadIdx.x;
    if (bid < 256) {
        float s1 = 0.f, s2 = 0.f, s3 = 0.f, s4 = 0.f;
        for (int m = tid; m < 1024; m += 256) {
            s1 += Wv[(size_t)bid * 1024 + m];
            s2 += Wv[(size_t)(bid + 256) * 1024 + m];
            s3 += Wv[(size_t)(bid + 512) * 1024 + m];
            s4 += Wv[(size_t)(bid + 768) * 1024 + m];
        }
        dreduce(s1, s2, shm);
        dreduce(s3, s4, shm);
        if (tid == 0) {
            wv_row[bid] = s1; wv_row[bid + 256] = s2;
            wv_row[bid + 512] = s3; wv_row[bid + 768] = s4;
        }
        if (bid == 0) {
            float v = 0.f, d2 = 0.f;
            for (int m = tid; m < 1024; m += 256) v += bv[m];
            dreduce(v, d2, shm);
            if (tid == 0) *bvsum = v;
        }
    } else {
        int t = bid & 255;
        int n0 = (t & 15) * 64, b0 = ((t >> 4) & 3) * 8, ks = t >> 6, k0 = ks * 256;
        load_A_global(shm, mem, b0, k0);
        __syncthreads();
        if (bid < 512)      nt_inner(shm, W0,  k0, n0, P1a, ks, b0);
        else if (bid < 768) nt_inner(shm, Wfb, k0, n0, Pfm, ks, b0);
        else                nt_inner(shm, Wub, k0, n0, Pum, ks, b0);
    }
}

// K2/K10: h@W1 partials with LN recompute from P. grid 256
__global__ void k_gemm_ln(const float* __restrict__ P, const float* __restrict__ bias,
                          const float* __restrict__ g, const float* __restrict__ be,
                          const float* __restrict__ W1, float* __restrict__ Pout) {
    __shared__ float shm[2080];
    int bid = blockIdx.x;
    int n0 = (bid & 15) * 64, b0 = ((bid >> 4) & 3) * 8, ks = bid >> 6, k0 = ks * 256;
    build_h_tile(shm, P, bias, g, be, b0, k0);
    nt_inner(shm, W1, k0, n0, Pout, ks, b0);
}

// K3: LN2 recompute + cb partial + mo@Wk^T slice. grid 512
__global__ void k_wpart(const float* __restrict__ P2a, const float* __restrict__ memb1,
                        const float* __restrict__ lng1, const float* __restrict__ lnb1,
                        const float* __restrict__ bk, const float* __restrict__ Wk,
                        float* __restrict__ wpart, float* __restrict__ cbpart) {
    __shared__ float shm[272];
    int bid = blockIdx.x, tid = threadIdx.x;
    int dc = bid & 3, b = (bid >> 2) & 31, mc = bid >> 7, m0 = mc * 256;
    float* Asl = shm; float* red = shm + 264;
    float s = 0.f, sq = 0.f;
    for (int m = tid; m < 1024; m += 256) {
        float z = memb1[m] + P2a[(size_t)b * 1024 + m] + P2a[(size_t)(32 + b) * 1024 + m]
                + P2a[(size_t)(64 + b) * 1024 + m] + P2a[(size_t)(96 + b) * 1024 + m];
        if ((unsigned)(m - m0) < 256u) Asl[m - m0] = z;
        s += z; sq += z * z;
    }
    dreduce(s, sq, red);
    float mean = s * (1.f / 1024.f);
    float rstd = rsqrtf(sq * (1.f / 1024.f) - mean * mean + LNEPS);
    {
        int m = m0 + tid;
        float xh = (Asl[tid] - mean) * rstd;
        float y = fmaf(xh, lng1[m], lnb1[m]);
        float sg = 1.f / (1.f + __expf(-y));
        Asl[tid] = y * sg;
    }
    __syncthreads();
    if (dc == 0) {
        float c = bk[m0 + tid] * Asl[tid], d2 = 0.f;
        dreduce(c, d2, red);
        if (tid == 0) cbpart[mc * 32 + b] = c;
    }
    int d = dc * 256 + tid;
    const float4* Wr = (const float4*)(Wk + (size_t)d * 1024 + m0);
    const float4* Ar = (const float4*)Asl;
    float acc = 0.f;
#pragma unroll 8
    for (int i = 0; i < 64; ++i) {
        float4 w4 = Wr[i], a4 = Ar[i];
        acc += w4.x * a4.x + w4.y * a4.y + w4.z * a4.z + w4.w * a4.w;
    }
    wpart[(size_t)(mc * 32 + b) * 1024 + d] = acc;
}

// K4: one pass over X. grid (32,32) -> bid = b*32+ch
__global__ void k_bigpass(const float* __restrict__ X, const float* __restrict__ wpart,
                          const float* __restrict__ wv_row, const float* __restrict__ cbpart,
                          const float* __restrict__ bvsum,
                          float* __restrict__ t_part, float* __restrict__ p_part,
                          float* __restrict__ rs_part) {
    __shared__ float red[4][1024];
    __shared__ float rsum_s[4];
    int b = blockIdx.y, ch = blockIdx.x;
    int wv = threadIdx.x >> 6, lane = threadIdx.x & 63;
    float4 wreg[4], tacc[4], pacc[4];
    const float4* wp4 = (const float4*)wpart;
    const float4* wr4 = (const float4*)wv_row;
#pragma unroll
    for (int j = 0; j < 4; ++j) {
        int d4 = lane + 64 * j;
        float4 s0 = wp4[((size_t)b) * 256 + d4];
        float4 s1 = wp4[((size_t)(32 + b)) * 256 + d4];
        float4 s2 = wp4[((size_t)(64 + b)) * 256 + d4];
        float4 s3 = wp4[((size_t)(96 + b)) * 256 + d4];
        float4 wr = wr4[d4];
        wreg[j].x = 1024.f * (s0.x + s1.x + s2.x + s3.x) - wr.x;
        wreg[j].y = 1024.f * (s0.y + s1.y + s2.y + s3.y) - wr.y;
        wreg[j].z = 1024.f * (s0.z + s1.z + s2.z + s3.z) - wr.z;
        wreg[j].w = 1024.f * (s0.w + s1.w + s2.w + s3.w) - wr.w;
        tacc[j] = make_float4(0.f, 0.f, 0.f, 0.f);
        pacc[j] = make_float4(0.f, 0.f, 0.f, 0.f);
    }
    float cbv = 1024.f * (cbpart[b] + cbpart[32 + b] + cbpart[64 + b] + cbpart[96 + b]) - *bvsum;
    float rloc = 0.f;
    int s0r = ch * 64 + wv * 16;
#pragma unroll 2
    for (int i = 0; i < 16; ++i) {
        const float4* xr = (const float4*)(X + ((size_t)b * Sc + s0r + i) * Dc);
        float4 x[4]; float pp = 0.f;
#pragma unroll
        for (int j = 0; j < 4; ++j) {
            x[j] = xr[lane + 64 * j];
            pp += x[j].x * wreg[j].x + x[j].y * wreg[j].y + x[j].z * wreg[j].z + x[j].w * wreg[j].w;
        }
#pragma unroll
        for (int o = 32; o; o >>= 1) pp += __shfl_xor(pp, o);
        float r = pp + cbv;
        rloc += r;
#pragma unroll
        for (int j = 0; j < 4; ++j) {
            tacc[j].x = fmaf(x[j].x, r, tacc[j].x);
            tacc[j].y = fmaf(x[j].y, r, tacc[j].y);
            tacc[j].z = fmaf(x[j].z, r, tacc[j].z);
            tacc[j].w = fmaf(x[j].w, r, tacc[j].w);
            pacc[j].x += x[j].x; pacc[j].y += x[j].y;
            pacc[j].z += x[j].z; pacc[j].w += x[j].w;
        }
    }
    float4* redv = (float4*)red[wv];
#pragma unroll
    for (int j = 0; j < 4; ++j) redv[lane + 64 * j] = tacc[j];
    if (lane == 0) rsum_s[wv] = rloc;
    __syncthreads();
    size_t pb = ((size_t)b * 32 + ch) * 1024;
    for (int j = 0; j < 4; ++j) {
        int d = threadIdx.x + 256 * j;
        t_part[pb + d] = red[0][d] + red[1][d] + red[2][d] + red[3][d];
    }
    if (threadIdx.x == 0) rs_part[b * 32 + ch] = rsum_s[0] + rsum_s[1] + rsum_s[2] + rsum_s[3];
    __syncthreads();
#pragma unroll
    for (int j = 0; j < 4; ++j) redv[lane + 64 * j] = pacc[j];
    __syncthreads();
    for (int j = 0; j < 4; ++j) {
        int d = threadIdx.x + 256 * j;
        p_part[pb + d] = red[0][d] + red[1][d] + red[2][d] + red[3][d];
    }
}

// K5: chunk reduce -> tbuf, pooled, rsv. grid 128
__global__ void k_reduce(const float* __restrict__ t_part, const float* __restrict__ p_part,
                         const float* __restrict__ rs_part,
                         float* __restrict__ tbuf, float* __restrict__ pooled,
                         float* __restrict__ rsv) {
    int idx = blockIdx.x * 256 + threadIdx.x, b = idx >> 10, d = idx & 1023;
    float st = 0.f, sp = 0.f;
    size_t base = (size_t)b * 32 * 1024 + d;
    for (int ch = 0; ch < 32; ++ch) {
        st += t_part[base + (size_t)ch * 1024];
        sp += p_part[base + (size_t)ch * 1024];
    }
    tbuf[idx] = st;
    pooled[idx] = sp * (1.f / 2048.f);
    if (blockIdx.x == 0 && threadIdx.x < 32) {
        float s = 0.f;
        for (int ch = 0; ch < 32; ++ch) s += rs_part[threadIdx.x * 32 + ch];
        rsv[threadIdx.x] = s;
    }
}

// K6: tbuf@Wk -> Pg ; pooled@Wf_top -> Pfp ; pooled@Wu_top -> Pup. grid 768
__global__ void k_gates(const float* __restrict__ tbuf, const float* __restrict__ pooled,
                        const float* __restrict__ Wk, const float* __restrict__ Wf,
                        const float* __restrict__ Wu,
                        float* __restrict__ Pg, float* __restrict__ Pfp, float* __restrict__ Pup) {
    __shared__ float shm[2080];
    int bid = blockIdx.x;
    int z = bid >> 8, t = bid & 255;
    int n0 = (t & 15) * 64, b0 = ((t >> 4) & 3) * 8, ks = t >> 6, k0 = ks * 256;
    const float* A = (z == 0) ? tbuf : pooled;
    load_A_global(shm, A, b0, k0);
    __syncthreads();
    if (z == 0)      nt_inner(shm, Wk, k0, n0, Pg, ks, b0);
    else if (z == 1) nt_inner(shm, Wf, k0, n0, Pfp, ks, b0);
    else             nt_inner(shm, Wu, k0, n0, Pup, ks, b0);
}

// K7/K8: LN-bwd recompute + gemm-T slice. grid 512
__global__ void k_lnbwd_gemmT(const float* __restrict__ Pz, const float* __restrict__ bias,
                              const float* __restrict__ g, const float* __restrict__ be,
                              const float* __restrict__ Pgrad, int mode,
                              const float* __restrict__ bk, const float* __restrict__ rsvp,
                              const float* __restrict__ W, float* __restrict__ Pout) {
    __shared__ float shm[2320];
    int bid = blockIdx.x, tid = threadIdx.x;
    int dc = bid & 3, b = (bid >> 2) & 31, mc = bid >> 7, m0 = mc * 256;
    float* zrow = shm;
    float* arow = shm + 1024;
    float* Asl = shm + 2048;
    float* red = shm + 2304;
    float s = 0.f, sq = 0.f;
    for (int m = tid; m < 1024; m += 256) {
        float z = bias[m] + Pz[(size_t)b * 1024 + m] + Pz[(size_t)(32 + b) * 1024 + m]
                + Pz[(size_t)(64 + b) * 1024 + m] + Pz[(size_t)(96 + b) * 1024 + m];
        zrow[m] = z; s += z; sq += z * z;
    }
    dreduce(s, sq, red);
    float mean = s * (1.f / 1024.f);
    float rstd = rsqrtf(sq * (1.f / 1024.f) - mean * mean + LNEPS);
    float rsb = mode ? rsvp[b] : 0.f;
    float sa = 0.f, sax = 0.f;
    for (int m = tid; m < 1024; m += 256) {
        float gv = Pgrad[(size_t)b * 1024 + m] + Pgrad[(size_t)(32 + b) * 1024 + m]
                 + Pgrad[(size_t)(64 + b) * 1024 + m] + Pgrad[(size_t)(96 + b) * 1024 + m];
        if (mode) gv = SCv * (gv + bk[m] * rsb);
        float xh = (zrow[m] - mean) * rstd;
        float y = fmaf(xh, g[m], be[m]);
        float sg = 1.f / (1.f + __expf(-y));
        float dsilu = sg * (1.f + y * (1.f - sg));
        float a = gv * dsilu * g[m];
        arow[m] = a; sa += a; sax += a * xh;
    }
    dreduce(sa, sax, red);
    float ma = sa * (1.f / 1024.f), mx = sax * (1.f / 1024.f);
    {
        int m = m0 + tid;
        float xh = (zrow[m] - mean) * rstd;
        Asl[tid] = rstd * (arow[m] - ma - xh * mx);
    }
    __syncthreads();
    int d = dc * 256 + tid;
    const float4* Wr = (const float4*)(W + (size_t)d * 1024 + m0);
    const float4* Ar = (const float4*)Asl;
    float acc = 0.f;
#pragma unroll 8
    for (int i = 0; i < 64; ++i) {
        float4 w4 = Wr[i], a4 = Ar[i];
        acc += w4.x * a4.x + w4.y * a4.y + w4.z * a4.z + w4.w * a4.w;
    }
    Pout[(size_t)(mc * 32 + b) * 1024 + d] = acc;
}

// K9: update recompute -> nmem tile -> nmem@W0 partials; writes out[BM:2BM]. grid 256
__global__ void k_upd_g3(const float* __restrict__ Pfm, const float* __restrict__ Pfp,
                         const float* __restrict__ Pum, const float* __restrict__ Pup,
                         const float* __restrict__ surp,
                         const float* __restrict__ bf, const float* __restrict__ bu,
                         const float* __restrict__ mem, const float* __restrict__ mom,
                         const float* __restrict__ eta, const float* __restrict__ theta,
                         const float* __restrict__ W0, float* __restrict__ P3a,
                         float* __restrict__ out_nm) {
    __shared__ float shm[2080];
    int bid = blockIdx.x, tid = threadIdx.x;
    int n0idx = bid & 15, n0 = n0idx * 64, b0 = ((bid >> 4) & 3) * 8, ks = bid >> 6, k0 = ks * 256;
    const size_t BM = (size_t)Bc * Mc;
    float etav = eta[0], thv = theta[0];
    for (int i = tid; i < 2048; i += 256) {
        int r = i >> 8, c = i & 255, b = b0 + r, m = k0 + c;
        size_t o = (size_t)b * 1024 + m;
        float zf = bf[m], zu = bu[m], sv = 0.f;
#pragma unroll
        for (int s4 = 0; s4 < 4; ++s4) {
            size_t ob = (size_t)s4 * BM + o;
            zf += Pfm[ob] + Pfp[ob];
            zu += Pum[ob] + Pup[ob];
            sv += surp[ob];
        }
        float f = 1.f / (1.f + __expf(-zf));
        float u = 1.f / (1.f + __expf(-zu));
        float nm = (1.f - f) * mem[o] + u * (etav * mom[o] + thv * sv);
        shm[i] = nm;
        if (n0idx == 0) out_nm[o] = nm;
    }
    __syncthreads();
    nt_inner(shm, W0, k0, n0, P3a, ks, b0);
}

// K11: final LN -> out. grid 32
__global__ void k_final(const float* __restrict__ P4a, const float* __restrict__ memb1,
                        const float* __restrict__ lng1, const float* __restrict__ lnb1,
                        float* __restrict__ out) {
    __shared__ float sm[8];
    int b = blockIdx.x, tid = threadIdx.x;
    float zv[4]; float s = 0.f, sq = 0.f;
    for (int j = 0; j < 4; ++j) {
        int m = tid + 256 * j;
        float z = memb1[m] + P4a[(size_t)b * 1024 + m] + P4a[(size_t)(32 + b) * 1024 + m]
                + P4a[(size_t)(64 + b) * 1024 + m] + P4a[(size_t)(96 + b) * 1024 + m];
        zv[j] = z; s += z; sq += z * z;
    }
    dreduce(s, sq, sm);
    float mean = s * (1.f / 1024.f);
    float rstd = rsqrtf(sq * (1.f / 1024.f) - mean * mean + LNEPS);
    for (int j = 0; j < 4; ++j) {
        int m = tid + 256 * j;
        float xh = (zv[j] - mean) * rstd;
        float y = fmaf(xh, lng1[m], lnb1[m]);
        float sg = 1.f / (1.f + __expf(-y));
        out[(size_t)b * 1024 + m] = y * sg;
    }
}

extern "C" void kernel_launch(void* const* d_in, const int* in_sizes, int n_in,
                              void* d_out, int out_size, void* d_ws, size_t ws_size,
                              hipStream_t stream) {
    const float* X    = (const float*)d_in[0];
    const float* mem  = (const float*)d_in[1];
    const float* mom  = (const float*)d_in[2];
    const float* Wk   = (const float*)d_in[3];
    const float* bk   = (const float*)d_in[4];
    const float* Wv   = (const float*)d_in[5];
    const float* bv   = (const float*)d_in[6];
    const float* memW = (const float*)d_in[7];
    const float* memb = (const float*)d_in[8];
    const float* lng  = (const float*)d_in[9];
    const float* lnb  = (const float*)d_in[10];
    const float* Wf   = (const float*)d_in[11];
    const float* bf   = (const float*)d_in[12];
    const float* Wu   = (const float*)d_in[15];
    const float* bu   = (const float*)d_in[16];
    const float* eta  = (const float*)d_in[17];
    const float* theta= (const float*)d_in[18];
    float* out = (float*)d_out;

    const size_t BM = (size_t)Bc * Mc;
    float* ws = (float*)d_ws;
    float* P1a    = ws;             // 4*BM
    float* P2a    = ws + 4 * BM;
    float* wpart  = ws + 8 * BM;
    float* Pg     = ws + 12 * BM;
    float* Pfp    = ws + 16 * BM;
    float* Pup    = ws + 20 * BM;
    float* Pfm    = ws + 24 * BM;
    float* Pum    = ws + 28 * BM;
    float* ghp    = ws + 32 * BM;
    float* surp   = ws + 36 * BM;
    float* P3a    = ws + 40 * BM;
    float* P4a    = ws + 44 * BM;
    float* tbuf   = ws + 48 * BM;
    float* pooled = ws + 49 * BM;
    float* wv_row = ws + 50 * BM;         // 1024
    float* bvsum  = wv_row + 1024;        // 1
    float* cbpart = bvsum + 1;            // 128
    float* rsv    = cbpart + 128;         // 32
    float* rs_part= rsv + 32;             // 1024
    float* t_part = ws + 52 * BM;         // 32*BM
    float* p_part = ws + 84 * BM;         // 32*BM

    const float* W0 = memW;
    const float* W1 = memW + (size_t)Mc * Mc;
    const float* Wfb = Wf + (size_t)1024 * 1024;
    const float* Wub = Wu + (size_t)1024 * 1024;

    k_front<<<1024, 256, 0, stream>>>(Wv, bv, mem, W0, Wfb, Wub, wv_row, bvsum, P1a, Pfm, Pum);
    k_gemm_ln<<<256, 256, 0, stream>>>(P1a, memb, lng, lnb, W1, P2a);
    k_wpart<<<512, 256, 0, stream>>>(P2a, memb + 1024, lng + 1024, lnb + 1024, bk, Wk, wpart, cbpart);
    k_bigpass<<<dim3(32, 32), 256, 0, stream>>>(X, wpart, wv_row, cbpart, bvsum, t_part, p_part, rs_part);
    k_reduce<<<128, 256, 0, stream>>>(t_part, p_part, rs_part, tbuf, pooled, rsv);
    k_gates<<<768, 256, 0, stream>>>(tbuf, pooled, Wk, Wf, Wu, Pg, Pfp, Pup);
    k_lnbwd_gemmT<<<512, 256, 0, stream>>>(P2a, memb + 1024, lng + 1024, lnb + 1024, Pg, 1, bk, rsv, W1, ghp);
    k_lnbwd_gemmT<<<512, 256, 0, stream>>>(P1a, memb, lng, lnb, ghp, 0, nullptr, nullptr, W0, surp);
    k_upd_g3<<<256, 256, 0, stream>>>(Pfm, Pfp, Pum, Pup, surp, bf, bu, mem, mom, eta, theta, W0, P3a, out + BM);
    k_gemm_ln<<<256, 256, 0, stream>>>(P3a, memb, lng, lnb, W1, P4a);
    k_final<<<32, 256, 0, stream>>>(P4a, memb + 1024, lng + 1024, lnb + 1024, out);
}

// Round 5
// 199.519 us; speedup vs baseline: 3.9940x; 1.2119x over previous
//
#include <hip/hip_runtime.h>
#include <math.h>

#define Bc 32
#define Sc 2048
#define Dc 1024
#define Mc 1024
#define LNEPS 1e-5f
#define SCv (1.f/67108864.f)   // 1/(B*S*M)

__device__ __forceinline__ float4 f4add(float4 a, float4 b) {
    return make_float4(a.x + b.x, a.y + b.y, a.z + b.z, a.w + b.w);
}

__device__ __forceinline__ void dreduce(float& a, float& b, float* sm) {
#pragma unroll
    for (int o = 32; o; o >>= 1) { a += __shfl_xor(a, o); b += __shfl_xor(b, o); }
    int w = threadIdx.x >> 6;
    if ((threadIdx.x & 63) == 0) { sm[w] = a; sm[4 + w] = b; }
    __syncthreads();
    a = sm[0] + sm[1] + sm[2] + sm[3];
    b = sm[4] + sm[5] + sm[6] + sm[7];
    __syncthreads();
}

__device__ __forceinline__ void wreduce(float& a, float& b) {
#pragma unroll
    for (int o = 32; o; o >>= 1) { a += __shfl_xor(a, o); b += __shfl_xor(b, o); }
}

// A-tile [8][128] from A[32][1024]
__device__ __forceinline__ void load_A128(float* Atile, const float* A, int b0, int k0) {
    for (int i = threadIdx.x; i < 1024; i += 256) {
        int r = i >> 7, c = i & 127;
        Atile[i] = A[(size_t)(b0 + r) * 1024 + k0 + c];
    }
}

// split-K NT inner (K-chunk 128): Atile[8][128] x W -> P[ks][b][n]
__device__ __forceinline__ void nt_inner128(const float* Atile, const float* W, int k0, int n0,
                                            float* P, int ks, int b0) {
    int n = n0 + (threadIdx.x & 63), bl = threadIdx.x >> 6;
    const float* a0 = Atile + bl * 128;
    const float* a1 = Atile + (bl + 4) * 128;
    const float* Wp = W + (size_t)k0 * 1024 + n;
    float acc0 = 0.f, acc1 = 0.f;
#pragma unroll 8
    for (int k = 0; k < 128; ++k) {
        float wv = Wp[(size_t)k * 1024];
        acc0 = fmaf(a0[k], wv, acc0);
        acc1 = fmaf(a1[k], wv, acc1);
    }
    size_t base = (size_t)ks * 32768 + n;
    P[base + (size_t)(b0 + bl) * 1024] = acc0;
    P[base + (size_t)(b0 + bl + 4) * 1024] = acc1;
}

// K1: wv_row/bvsum (bid<256) + mem@W0 partials (512 blocks). grid 768
__global__ __launch_bounds__(256) void k_front(const float* __restrict__ Wv, const float* __restrict__ bv,
                        const float* __restrict__ mem, const float* __restrict__ W0,
                        float* __restrict__ wv_row, float* __restrict__ bvsum,
                        float* __restrict__ P1a) {
    __shared__ float shm[1032];
    int bid = blockIdx.x, tid = threadIdx.x;
    if (bid < 256) {
        float s1 = 0.f, s2 = 0.f, s3 = 0.f, s4 = 0.f;
        for (int m = tid; m < 1024; m += 256) {
            s1 += Wv[(size_t)bid * 1024 + m];
            s2 += Wv[(size_t)(bid + 256) * 1024 + m];
            s3 += Wv[(size_t)(bid + 512) * 1024 + m];
            s4 += Wv[(size_t)(bid + 768) * 1024 + m];
        }
        dreduce(s1, s2, shm + 1024);
        dreduce(s3, s4, shm + 1024);
        if (tid == 0) {
            wv_row[bid] = s1; wv_row[bid + 256] = s2;
            wv_row[bid + 512] = s3; wv_row[bid + 768] = s4;
        }
        if (bid == 0) {
            float v = 0.f, d2 = 0.f;
            for (int m = tid; m < 1024; m += 256) v += bv[m];
            dreduce(v, d2, shm + 1024);
            if (tid == 0) *bvsum = v;
        }
    } else {
        int t = bid - 256;
        int n0 = (t & 15) * 64, b0 = ((t >> 4) & 3) * 8, ks = t >> 6, k0 = ks * 128;
        load_A128(shm, mem, b0, k0);
        __syncthreads();
        nt_inner128(shm, W0, k0, n0, P1a, ks, b0);
    }
}

// K2/K9: h = SiLU(LN(bias + sum8 P)) tile, then @W1 -> Pout. grid 512
__global__ __launch_bounds__(256) void k_gemm_ln(const float* __restrict__ P, const float* __restrict__ bias,
                          const float* __restrict__ g, const float* __restrict__ be,
                          const float* __restrict__ W1, float* __restrict__ Pout) {
    __shared__ float shm[1040];
    int bid = blockIdx.x, tid = threadIdx.x;
    int n0 = (bid & 15) * 64, b0 = ((bid >> 4) & 3) * 8, ks = bid >> 6, k0 = ks * 128;
    float* Atile = shm; float* stats = shm + 1024;
    int wv = tid >> 6, lane = tid & 63;
    const float4* b4 = (const float4*)bias;
    for (int rr = 0; rr < 2; ++rr) {
        int r = wv + rr * 4, b = b0 + r;
        float s = 0.f, sq = 0.f;
#pragma unroll
        for (int q = 0; q < 4; ++q) {
            int m4 = lane + 64 * q;
            float4 z4 = b4[m4];
#pragma unroll
            for (int k2 = 0; k2 < 8; ++k2) {
                float4 v = ((const float4*)(P + (size_t)k2 * 32768 + (size_t)b * 1024))[m4];
                z4 = f4add(z4, v);
            }
            int c0 = 4 * m4 - k0;
            if ((unsigned)c0 < 128u) *(float4*)(Atile + r * 128 + c0) = z4;
            s += z4.x + z4.y + z4.z + z4.w;
            sq += z4.x * z4.x + z4.y * z4.y + z4.z * z4.z + z4.w * z4.w;
        }
        wreduce(s, sq);
        if (lane == 0) {
            float mean = s * (1.f / 1024.f);
            stats[r] = mean;
            stats[8 + r] = rsqrtf(sq * (1.f / 1024.f) - mean * mean + LNEPS);
        }
    }
    __syncthreads();
    for (int i = tid; i < 1024; i += 256) {
        int r = i >> 7, c = i & 127, m = k0 + c;
        float xh = (Atile[i] - stats[r]) * stats[8 + r];
        float y = fmaf(xh, g[m], be[m]);
        float sg = 1.f / (1.f + __expf(-y));
        Atile[i] = y * sg;
    }
    __syncthreads();
    nt_inner128(Atile, W1, k0, n0, Pout, ks, b0);
}

// K3: LN2 recompute + cb partial + mo@Wk^T slice. grid 1024 (dc4 x b32 x mc8)
__global__ __launch_bounds__(256) void k_wpart(const float* __restrict__ P2a, const float* __restrict__ memb1,
                        const float* __restrict__ lng1, const float* __restrict__ lnb1,
                        const float* __restrict__ bk, const float* __restrict__ Wk,
                        float* __restrict__ wpart, float* __restrict__ cbpart) {
    __shared__ float shm[136];
    int bid = blockIdx.x, tid = threadIdx.x;
    int dc = bid & 3, b = (bid >> 2) & 31, mc = bid >> 7, m0 = mc * 128;
    float* red = shm + 128;
    float4 z4 = ((const float4*)memb1)[tid];
#pragma unroll
    for (int k2 = 0; k2 < 8; ++k2) {
        float4 v = ((const float4*)(P2a + (size_t)k2 * 32768 + (size_t)b * 1024))[tid];
        z4 = f4add(z4, v);
    }
    float s = z4.x + z4.y + z4.z + z4.w;
    float sq = z4.x * z4.x + z4.y * z4.y + z4.z * z4.z + z4.w * z4.w;
    int c0 = 4 * tid - m0;
    if ((unsigned)c0 < 128u) *(float4*)(shm + c0) = z4;
    dreduce(s, sq, red);
    float mean = s * (1.f / 1024.f);
    float rstd = rsqrtf(sq * (1.f / 1024.f) - mean * mean + LNEPS);
    if (tid < 128) {
        int m = m0 + tid;
        float xh = (shm[tid] - mean) * rstd;
        float y = fmaf(xh, lng1[m], lnb1[m]);
        float sg = 1.f / (1.f + __expf(-y));
        shm[tid] = y * sg;
    }
    __syncthreads();
    if (dc == 0) {
        float c = (tid < 128) ? bk[m0 + tid] * shm[tid] : 0.f;
        float d2 = 0.f;
        dreduce(c, d2, red);
        if (tid == 0) cbpart[mc * 32 + b] = c;
    }
    int d = dc * 256 + tid;
    const float4* Wr = (const float4*)(Wk + (size_t)d * 1024 + m0);
    const float4* Ar = (const float4*)shm;
    float acc = 0.f;
#pragma unroll 8
    for (int i = 0; i < 32; ++i) {
        float4 w4 = Wr[i], a4 = Ar[i];
        acc += w4.x * a4.x + w4.y * a4.y + w4.z * a4.z + w4.w * a4.w;
    }
    wpart[(size_t)(mc * 32 + b) * 1024 + d] = acc;
}

// K4: one pass over X. grid (32,32)
__global__ __launch_bounds__(256) void k_bigpass(const float* __restrict__ X, const float* __restrict__ wpart,
                          const float* __restrict__ wv_row, const float* __restrict__ cbpart,
                          const float* __restrict__ bvsum,
                          float* __restrict__ t_part, float* __restrict__ p_part,
                          float* __restrict__ rs_part) {
    __shared__ float red[4][1024];
    __shared__ float rsum_s[4];
    int b = blockIdx.y, ch = blockIdx.x;
    int wv = threadIdx.x >> 6, lane = threadIdx.x & 63;
    float4 wreg[4], tacc[4], pacc[4];
    const float4* wp4 = (const float4*)wpart;
    const float4* wr4 = (const float4*)wv_row;
#pragma unroll
    for (int j = 0; j < 4; ++j) {
        int d4 = lane + 64 * j;
        float4 a = make_float4(0.f, 0.f, 0.f, 0.f);
#pragma unroll
        for (int mc = 0; mc < 8; ++mc) a = f4add(a, wp4[(size_t)(mc * 32 + b) * 256 + d4]);
        float4 wr = wr4[d4];
        wreg[j].x = 1024.f * a.x - wr.x;
        wreg[j].y = 1024.f * a.y - wr.y;
        wreg[j].z = 1024.f * a.z - wr.z;
        wreg[j].w = 1024.f * a.w - wr.w;
        tacc[j] = make_float4(0.f, 0.f, 0.f, 0.f);
        pacc[j] = make_float4(0.f, 0.f, 0.f, 0.f);
    }
    float cbs = 0.f;
#pragma unroll
    for (int mc = 0; mc < 8; ++mc) cbs += cbpart[mc * 32 + b];
    float cbv = 1024.f * cbs - *bvsum;
    float rloc = 0.f;
    int s0r = ch * 64 + wv * 16;
#pragma unroll 2
    for (int i = 0; i < 16; ++i) {
        const float4* xr = (const float4*)(X + ((size_t)b * Sc + s0r + i) * Dc);
        float4 x[4]; float pp = 0.f;
#pragma unroll
        for (int j = 0; j < 4; ++j) {
            x[j] = xr[lane + 64 * j];
            pp += x[j].x * wreg[j].x + x[j].y * wreg[j].y + x[j].z * wreg[j].z + x[j].w * wreg[j].w;
        }
#pragma unroll
        for (int o = 32; o; o >>= 1) pp += __shfl_xor(pp, o);
        float r = pp + cbv;
        rloc += r;
#pragma unroll
        for (int j = 0; j < 4; ++j) {
            tacc[j].x = fmaf(x[j].x, r, tacc[j].x);
            tacc[j].y = fmaf(x[j].y, r, tacc[j].y);
            tacc[j].z = fmaf(x[j].z, r, tacc[j].z);
            tacc[j].w = fmaf(x[j].w, r, tacc[j].w);
            pacc[j].x += x[j].x; pacc[j].y += x[j].y;
            pacc[j].z += x[j].z; pacc[j].w += x[j].w;
        }
    }
    float4* redv = (float4*)red[wv];
#pragma unroll
    for (int j = 0; j < 4; ++j) redv[lane + 64 * j] = tacc[j];
    if (lane == 0) rsum_s[wv] = rloc;
    __syncthreads();
    size_t pb = ((size_t)b * 32 + ch) * 1024;
    for (int j = 0; j < 4; ++j) {
        int d = threadIdx.x + 256 * j;
        t_part[pb + d] = red[0][d] + red[1][d] + red[2][d] + red[3][d];
    }
    if (threadIdx.x == 0) rs_part[b * 32 + ch] = rsum_s[0] + rsum_s[1] + rsum_s[2] + rsum_s[3];
    __syncthreads();
#pragma unroll
    for (int j = 0; j < 4; ++j) redv[lane + 64 * j] = pacc[j];
    __syncthreads();
    for (int j = 0; j < 4; ++j) {
        int d = threadIdx.x + 256 * j;
        p_part[pb + d] = red[0][d] + red[1][d] + red[2][d] + red[3][d];
    }
}

// K5: 5 GEMMs in one launch; z<3 self-reduce slab from t_part/p_part. grid 2560
__global__ __launch_bounds__(256) void k_gates(const float* __restrict__ t_part, const float* __restrict__ p_part,
                        const float* __restrict__ mem,
                        const float* __restrict__ Wk, const float* __restrict__ Wf,
                        const float* __restrict__ Wu,
                        float* __restrict__ Pg, float* __restrict__ Pfp, float* __restrict__ Pup,
                        float* __restrict__ Pfm, float* __restrict__ Pum) {
    __shared__ float Atile[1024];
    int bid = blockIdx.x, tid = threadIdx.x;
    int z = bid >> 9, t = bid & 511;
    int n0 = (t & 15) * 64, b0 = ((t >> 4) & 3) * 8, ks = t >> 6, k0 = ks * 128;
    if (z >= 3) {
        load_A128(Atile, mem, b0, k0);
        __syncthreads();
        if (z == 3) nt_inner128(Atile, Wf + (size_t)1024 * 1024, k0, n0, Pfm, ks, b0);
        else        nt_inner128(Atile, Wu + (size_t)1024 * 1024, k0, n0, Pum, ks, b0);
        return;
    }
    const float* src = (z == 0) ? t_part : p_part;
    float scale = (z == 0) ? 1.f : (1.f / 2048.f);
    {
        int r = tid >> 5, c4 = tid & 31;
        int b = b0 + r;
        const float4* base = (const float4*)(src + (size_t)b * 32 * 1024 + k0) + c4;
        float4 acc = make_float4(0.f, 0.f, 0.f, 0.f);
#pragma unroll 8
        for (int ch = 0; ch < 32; ++ch) acc = f4add(acc, base[(size_t)ch * 256]);
        acc.x *= scale; acc.y *= scale; acc.z *= scale; acc.w *= scale;
        *(float4*)(Atile + r * 128 + 4 * c4) = acc;
    }
    __syncthreads();
    if (z == 0)      nt_inner128(Atile, Wk, k0, n0, Pg, ks, b0);
    else if (z == 1) nt_inner128(Atile, Wf, k0, n0, Pfp, ks, b0);
    else             nt_inner128(Atile, Wu, k0, n0, Pup, ks, b0);
}

// K6/K7: LN-bwd recompute (+rsv self-reduce) + gemm-T slice. grid 1024
__global__ __launch_bounds__(256) void k_lnbwd_gemmT(const float* __restrict__ Pz, const float* __restrict__ bias,
                              const float* __restrict__ g, const float* __restrict__ be,
                              const float* __restrict__ Pgrad, int mode,
                              const float* __restrict__ bk, const float* __restrict__ rs_part,
                              const float* __restrict__ W, float* __restrict__ Pout) {
    __shared__ float shm[392];
    int bid = blockIdx.x, tid = threadIdx.x;
    int dc = bid & 3, b = (bid >> 2) & 31, mc = bid >> 7, m0 = mc * 128;
    float* red = shm + 384;
    float rsb = 0.f;
    if (mode) {
        float v = (tid < 32) ? rs_part[b * 32 + tid] : 0.f, d2 = 0.f;
        dreduce(v, d2, red);
        rsb = v;
    }
    float4 z4 = ((const float4*)bias)[tid];
#pragma unroll
    for (int k2 = 0; k2 < 8; ++k2) {
        float4 v = ((const float4*)(Pz + (size_t)k2 * 32768 + (size_t)b * 1024))[tid];
        z4 = f4add(z4, v);
    }
    float s = z4.x + z4.y + z4.z + z4.w;
    float sq = z4.x * z4.x + z4.y * z4.y + z4.z * z4.z + z4.w * z4.w;
    dreduce(s, sq, red);
    float mean = s * (1.f / 1024.f);
    float rstd = rsqrtf(sq * (1.f / 1024.f) - mean * mean + LNEPS);
    float4 g4 = make_float4(0.f, 0.f, 0.f, 0.f);
#pragma unroll
    for (int k2 = 0; k2 < 8; ++k2) {
        float4 v = ((const float4*)(Pgrad + (size_t)k2 * 32768 + (size_t)b * 1024))[tid];
        g4 = f4add(g4, v);
    }
    if (mode) {
        float4 bk4 = ((const float4*)bk)[tid];
        g4.x = SCv * (g4.x + bk4.x * rsb);
        g4.y = SCv * (g4.y + bk4.y * rsb);
        g4.z = SCv * (g4.z + bk4.z * rsb);
        g4.w = SCv * (g4.w + bk4.w * rsb);
    }
    float4 gg = ((const float4*)g)[tid], bb = ((const float4*)be)[tid];
    float sa = 0.f, sax = 0.f;
    float4 a4, xh4;
    {
        xh4.x = (z4.x - mean) * rstd;
        float y = fmaf(xh4.x, gg.x, bb.x);
        float sg2 = 1.f / (1.f + __expf(-y));
        a4.x = g4.x * (sg2 * (1.f + y * (1.f - sg2))) * gg.x;
        sa += a4.x; sax += a4.x * xh4.x;
        xh4.y = (z4.y - mean) * rstd;
        y = fmaf(xh4.y, gg.y, bb.y);
        sg2 = 1.f / (1.f + __expf(-y));
        a4.y = g4.y * (sg2 * (1.f + y * (1.f - sg2))) * gg.y;
        sa += a4.y; sax += a4.y * xh4.y;
        xh4.z = (z4.z - mean) * rstd;
        y = fmaf(xh4.z, gg.z, bb.z);
        sg2 = 1.f / (1.f + __expf(-y));
        a4.z = g4.z * (sg2 * (1.f + y * (1.f - sg2))) * gg.z;
        sa += a4.z; sax += a4.z * xh4.z;
        xh4.w = (z4.w - mean) * rstd;
        y = fmaf(xh4.w, gg.w, bb.w);
        sg2 = 1.f / (1.f + __expf(-y));
        a4.w = g4.w * (sg2 * (1.f + y * (1.f - sg2))) * gg.w;
        sa += a4.w; sax += a4.w * xh4.w;
    }
    int c0 = 4 * tid - m0;
    if ((unsigned)c0 < 128u) {
        *(float4*)(shm + c0) = a4;
        *(float4*)(shm + 128 + c0) = xh4;
    }
    dreduce(sa, sax, red);
    float ma = sa * (1.f / 1024.f), mx = sax * (1.f / 1024.f);
    if (tid < 128) shm[256 + tid] = rstd * (shm[tid] - ma - shm[128 + tid] * mx);
    __syncthreads();
    int d = dc * 256 + tid;
    const float4* Wr = (const float4*)(W + (size_t)d * 1024 + m0);
    const float4* Ar = (const float4*)(shm + 256);
    float acc = 0.f;
#pragma unroll 8
    for (int i = 0; i < 32; ++i) {
        float4 w4 = Wr[i], A4 = Ar[i];
        acc += w4.x * A4.x + w4.y * A4.y + w4.z * A4.z + w4.w * A4.w;
    }
    Pout[(size_t)(mc * 32 + b) * 1024 + d] = acc;
}

// K8: gate/update recompute -> nmem tile -> @W0 partials; writes out_nm. grid 512
__global__ __launch_bounds__(256) void k_upd_g3(const float* __restrict__ Pfm, const float* __restrict__ Pfp,
                         const float* __restrict__ Pum, const float* __restrict__ Pup,
                         const float* __restrict__ surp,
                         const float* __restrict__ bf, const float* __restrict__ bu,
                         const float* __restrict__ mem, const float* __restrict__ mom,
                         const float* __restrict__ eta, const float* __restrict__ theta,
                         const float* __restrict__ W0, float* __restrict__ P3a,
                         float* __restrict__ out_nm) {
    __shared__ float Atile[1024];
    int bid = blockIdx.x, tid = threadIdx.x;
    int n0idx = bid & 15, n0 = n0idx * 64, b0 = ((bid >> 4) & 3) * 8, ks = bid >> 6, k0 = ks * 128;
    float etav = eta[0], thv = theta[0];
    int r = tid >> 5, c4 = tid & 31, b = b0 + r;
    int m4 = (k0 >> 2) + c4;
    float4 zf = ((const float4*)bf)[m4];
    float4 zu = ((const float4*)bu)[m4];
    float4 sv = make_float4(0.f, 0.f, 0.f, 0.f);
#pragma unroll
    for (int k2 = 0; k2 < 8; ++k2) {
        size_t ob4 = (size_t)k2 * 8192 + (size_t)b * 256 + m4;
        zf = f4add(zf, f4add(((const float4*)Pfm)[ob4], ((const float4*)Pfp)[ob4]));
        zu = f4add(zu, f4add(((const float4*)Pum)[ob4], ((const float4*)Pup)[ob4]));
        sv = f4add(sv, ((const float4*)surp)[ob4]);
    }
    float4 me = ((const float4*)mem)[(size_t)b * 256 + m4];
    float4 mo = ((const float4*)mom)[(size_t)b * 256 + m4];
    float4 nm;
    {
        float f = 1.f / (1.f + __expf(-zf.x)), u = 1.f / (1.f + __expf(-zu.x));
        nm.x = (1.f - f) * me.x + u * (etav * mo.x + thv * sv.x);
        f = 1.f / (1.f + __expf(-zf.y)); u = 1.f / (1.f + __expf(-zu.y));
        nm.y = (1.f - f) * me.y + u * (etav * mo.y + thv * sv.y);
        f = 1.f / (1.f + __expf(-zf.z)); u = 1.f / (1.f + __expf(-zu.z));
        nm.z = (1.f - f) * me.z + u * (etav * mo.z + thv * sv.z);
        f = 1.f / (1.f + __expf(-zf.w)); u = 1.f / (1.f + __expf(-zu.w));
        nm.w = (1.f - f) * me.w + u * (etav * mo.w + thv * sv.w);
    }
    *(float4*)(Atile + r * 128 + 4 * c4) = nm;
    if (n0idx == 0) ((float4*)out_nm)[(size_t)b * 256 + m4] = nm;
    __syncthreads();
    nt_inner128(Atile, W0, k0, n0, P3a, ks, b0);
}

// K10: final LN -> out. grid 32
__global__ __launch_bounds__(256) void k_final(const float* __restrict__ P4a, const float* __restrict__ memb1,
                        const float* __restrict__ lng1, const float* __restrict__ lnb1,
                        float* __restrict__ out) {
    __shared__ float sm[8];
    int b = blockIdx.x, tid = threadIdx.x;
    float4 z4 = ((const float4*)memb1)[tid];
#pragma unroll
    for (int k2 = 0; k2 < 8; ++k2) {
        float4 v = ((const float4*)(P4a + (size_t)k2 * 32768 + (size_t)b * 1024))[tid];
        z4 = f4add(z4, v);
    }
    float s = z4.x + z4.y + z4.z + z4.w;
    float sq = z4.x * z4.x + z4.y * z4.y + z4.z * z4.z + z4.w * z4.w;
    dreduce(s, sq, sm);
    float mean = s * (1.f / 1024.f);
    float rstd = rsqrtf(sq * (1.f / 1024.f) - mean * mean + LNEPS);
    float4 gg = ((const float4*)lng1)[tid], bb = ((const float4*)lnb1)[tid];
    float4 o;
    {
        float xh = (z4.x - mean) * rstd, y = fmaf(xh, gg.x, bb.x);
        o.x = y / (1.f + __expf(-y));
        xh = (z4.y - mean) * rstd; y = fmaf(xh, gg.y, bb.y);
        o.y = y / (1.f + __expf(-y));
        xh = (z4.z - mean) * rstd; y = fmaf(xh, gg.z, bb.z);
        o.z = y / (1.f + __expf(-y));
        xh = (z4.w - mean) * rstd; y = fmaf(xh, gg.w, bb.w);
        o.w = y / (1.f + __expf(-y));
    }
    ((float4*)out)[(size_t)b * 256 + tid] = o;
}

extern "C" void kernel_launch(void* const* d_in, const int* in_sizes, int n_in,
                              void* d_out, int out_size, void* d_ws, size_t ws_size,
                              hipStream_t stream) {
    const float* X    = (const float*)d_in[0];
    const float* mem  = (const float*)d_in[1];
    const float* mom  = (const float*)d_in[2];
    const float* Wk   = (const float*)d_in[3];
    const float* bk   = (const float*)d_in[4];
    const float* Wv   = (const float*)d_in[5];
    const float* bv   = (const float*)d_in[6];
    const float* memW = (const float*)d_in[7];
    const float* memb = (const float*)d_in[8];
    const float* lng  = (const float*)d_in[9];
    const float* lnb  = (const float*)d_in[10];
    const float* Wf   = (const float*)d_in[11];
    const float* bf   = (const float*)d_in[12];
    const float* Wu   = (const float*)d_in[15];
    const float* bu   = (const float*)d_in[16];
    const float* eta  = (const float*)d_in[17];
    const float* theta= (const float*)d_in[18];
    float* out = (float*)d_out;

    const size_t BM = (size_t)Bc * Mc;     // 32768
    float* ws = (float*)d_ws;
    float* P1a    = ws;                    // 8*BM each
    float* P2a    = ws + 8 * BM;
    float* wpart  = ws + 16 * BM;
    float* Pg     = ws + 24 * BM;
    float* Pfp    = ws + 32 * BM;
    float* Pup    = ws + 40 * BM;
    float* Pfm    = ws + 48 * BM;
    float* Pum    = ws + 56 * BM;
    float* ghp    = ws + 64 * BM;
    float* surp   = ws + 72 * BM;
    float* P3a    = ws + 80 * BM;
    float* P4a    = ws + 88 * BM;
    float* t_part = ws + 96 * BM;          // 32*BM
    float* p_part = ws + 128 * BM;         // 32*BM
    float* wv_row = ws + 160 * BM;         // 1024
    float* bvsum  = wv_row + 1024;         // 1
    float* cbpart = bvsum + 1;             // 256
    float* rs_part= cbpart + 256;          // 1024

    const float* W0 = memW;
    const float* W1 = memW + (size_t)Mc * Mc;

    k_front<<<768, 256, 0, stream>>>(Wv, bv, mem, W0, wv_row, bvsum, P1a);
    k_gemm_ln<<<512, 256, 0, stream>>>(P1a, memb, lng, lnb, W1, P2a);
    k_wpart<<<1024, 256, 0, stream>>>(P2a, memb + 1024, lng + 1024, lnb + 1024, bk, Wk, wpart, cbpart);
    k_bigpass<<<dim3(32, 32), 256, 0, stream>>>(X, wpart, wv_row, cbpart, bvsum, t_part, p_part, rs_part);
    k_gates<<<2560, 256, 0, stream>>>(t_part, p_part, mem, Wk, Wf, Wu, Pg, Pfp, Pup, Pfm, Pum);
    k_lnbwd_gemmT<<<1024, 256, 0, stream>>>(P2a, memb + 1024, lng + 1024, lnb + 1024, Pg, 1, bk, rs_part, W1, ghp);
    k_lnbwd_gemmT<<<1024, 256, 0, stream>>>(P1a, memb, lng, lnb, ghp, 0, bk, rs_part, W0, surp);
    k_upd_g3<<<512, 256, 0, stream>>>(Pfm, Pfp, Pum, Pup, surp, bf, bu, mem, mom, eta, theta, W0, P3a, out + BM);
    k_gemm_ln<<<512, 256, 0, stream>>>(P3a, memb, lng, lnb, W1, P4a);
    k_final<<<32, 256, 0, stream>>>(P4a, memb + 1024, lng + 1024, lnb + 1024, out);
}

// Round 6
// 165.262 us; speedup vs baseline: 4.8219x; 1.2073x over previous
//
#include <hip/hip_runtime.h>
#include <math.h>

#define Bc 32
#define Sc 2048
#define Dc 1024
#define Mc 1024
#define LNEPS 1e-5f
#define SCv (1.f/67108864.f)   // 1/(B*S*M)

__device__ __forceinline__ float4 f4add(float4 a, float4 b) {
    return make_float4(a.x + b.x, a.y + b.y, a.z + b.z, a.w + b.w);
}

__device__ __forceinline__ void dreduce(float& a, float& b, float* sm) {
#pragma unroll
    for (int o = 32; o; o >>= 1) { a += __shfl_xor(a, o); b += __shfl_xor(b, o); }
    int w = threadIdx.x >> 6;
    if ((threadIdx.x & 63) == 0) { sm[w] = a; sm[4 + w] = b; }
    __syncthreads();
    a = sm[0] + sm[1] + sm[2] + sm[3];
    b = sm[4] + sm[5] + sm[6] + sm[7];
    __syncthreads();
}

__device__ __forceinline__ void wreduce(float& a, float& b) {
#pragma unroll
    for (int o = 32; o; o >>= 1) { a += __shfl_xor(a, o); b += __shfl_xor(b, o); }
}

// A-tile [8][128] from A[32][1024]
__device__ __forceinline__ void load_A128(float* Atile, const float* A, int b0, int k0) {
    for (int i = threadIdx.x; i < 1024; i += 256) {
        int r = i >> 7, c = i & 127;
        Atile[i] = A[(size_t)(b0 + r) * 1024 + k0 + c];
    }
}

// NT inner v2: Atile[8][128] x W[k0..k0+127][n0..n0+63] -> P[ks][b][n]
// lane = kg(2b)|n4(4b): float4 W loads (4 rows x 256B contiguous per wave-iter),
// k-group partial sums folded by shfl_xor(16),(32).
__device__ __forceinline__ void nt_inner128v(const float* Atile, const float* W, int k0, int n0,
                                             float* P, int ks, int b0) {
    int lane = threadIdx.x & 63, bl = threadIdx.x >> 6;
    int n4 = lane & 15, kg = lane >> 4;
    const float* a0 = Atile + bl * 128;
    const float* a1 = Atile + (bl + 4) * 128;
    const float4* Wp = (const float4*)(W + (size_t)k0 * 1024 + n0);
    float4 acc0 = make_float4(0.f, 0.f, 0.f, 0.f);
    float4 acc1 = make_float4(0.f, 0.f, 0.f, 0.f);
#pragma unroll 8
    for (int i = 0; i < 32; ++i) {
        int k = i * 4 + kg;
        float4 w4 = Wp[(size_t)k * 256 + n4];
        float av0 = a0[k], av1 = a1[k];
        acc0.x = fmaf(av0, w4.x, acc0.x); acc0.y = fmaf(av0, w4.y, acc0.y);
        acc0.z = fmaf(av0, w4.z, acc0.z); acc0.w = fmaf(av0, w4.w, acc0.w);
        acc1.x = fmaf(av1, w4.x, acc1.x); acc1.y = fmaf(av1, w4.y, acc1.y);
        acc1.z = fmaf(av1, w4.z, acc1.z); acc1.w = fmaf(av1, w4.w, acc1.w);
    }
#pragma unroll
    for (int o = 16; o <= 32; o <<= 1) {
        acc0.x += __shfl_xor(acc0.x, o); acc0.y += __shfl_xor(acc0.y, o);
        acc0.z += __shfl_xor(acc0.z, o); acc0.w += __shfl_xor(acc0.w, o);
        acc1.x += __shfl_xor(acc1.x, o); acc1.y += __shfl_xor(acc1.y, o);
        acc1.z += __shfl_xor(acc1.z, o); acc1.w += __shfl_xor(acc1.w, o);
    }
    if (kg == 0) {
        size_t base = (size_t)ks * 32768 + n0 + 4 * n4;
        *(float4*)&P[base + (size_t)(b0 + bl) * 1024] = acc0;
        *(float4*)&P[base + (size_t)(b0 + bl + 4) * 1024] = acc1;
    }
}

// T inner v2: out[d] = sum_{m in [m0,m0+128)} Asl[m-m0]*W[d*1024+m], 256 d's per block.
// Wave wv covers d-range [dbase+wv*64, +64); per pass reads 2 full W-row chunks
// (contiguous 512B each), 5-step half-wave shfl reduce.
__device__ __forceinline__ void t_inner(const float* Asl, const float* W,
                                        int dbase, int m0, float* outp) {
    int lane = threadIdx.x & 63, wv = threadIdx.x >> 6;
    int half = lane >> 5, m4 = lane & 31;
    float4 a4 = ((const float4*)Asl)[m4];
    int d0 = dbase + wv * 64 + half;
    float res = 0.f;
#pragma unroll 8
    for (int p = 0; p < 32; ++p) {
        int d = d0 + p * 2;
        float4 w4 = ((const float4*)(W + (size_t)d * 1024 + m0))[m4];
        float v = w4.x * a4.x + w4.y * a4.y + w4.z * a4.z + w4.w * a4.w;
#pragma unroll
        for (int o = 1; o < 32; o <<= 1) v += __shfl_xor(v, o);
        res = (m4 == p) ? v : res;
    }
    outp[wv * 64 + m4 * 2 + half] = res;
}

// K1: wv_row/bvsum (bid<256) + mem@W0 partials (512 blocks). grid 768
__global__ __launch_bounds__(256) void k_front(const float* __restrict__ Wv, const float* __restrict__ bv,
                        const float* __restrict__ mem, const float* __restrict__ W0,
                        float* __restrict__ wv_row, float* __restrict__ bvsum,
                        float* __restrict__ P1a) {
    __shared__ float shm[1032];
    int bid = blockIdx.x, tid = threadIdx.x;
    if (bid < 256) {
        float s1 = 0.f, s2 = 0.f, s3 = 0.f, s4 = 0.f;
        for (int m = tid; m < 1024; m += 256) {
            s1 += Wv[(size_t)bid * 1024 + m];
            s2 += Wv[(size_t)(bid + 256) * 1024 + m];
            s3 += Wv[(size_t)(bid + 512) * 1024 + m];
            s4 += Wv[(size_t)(bid + 768) * 1024 + m];
        }
        dreduce(s1, s2, shm + 1024);
        dreduce(s3, s4, shm + 1024);
        if (tid == 0) {
            wv_row[bid] = s1; wv_row[bid + 256] = s2;
            wv_row[bid + 512] = s3; wv_row[bid + 768] = s4;
        }
        if (bid == 0) {
            float v = 0.f, d2 = 0.f;
            for (int m = tid; m < 1024; m += 256) v += bv[m];
            dreduce(v, d2, shm + 1024);
            if (tid == 0) *bvsum = v;
        }
    } else {
        int t = bid - 256;
        int n0 = (t & 15) * 64, b0 = ((t >> 4) & 3) * 8, ks = t >> 6, k0 = ks * 128;
        load_A128(shm, mem, b0, k0);
        __syncthreads();
        nt_inner128v(shm, W0, k0, n0, P1a, ks, b0);
    }
}

// K2/K9: h = SiLU(LN(bias + sum8 P)) tile, then @W1 -> Pout. grid 512
__global__ __launch_bounds__(256) void k_gemm_ln(const float* __restrict__ P, const float* __restrict__ bias,
                          const float* __restrict__ g, const float* __restrict__ be,
                          const float* __restrict__ W1, float* __restrict__ Pout) {
    __shared__ float shm[1040];
    int bid = blockIdx.x, tid = threadIdx.x;
    int n0 = (bid & 15) * 64, b0 = ((bid >> 4) & 3) * 8, ks = bid >> 6, k0 = ks * 128;
    float* Atile = shm; float* stats = shm + 1024;
    int wv = tid >> 6, lane = tid & 63;
    const float4* b4 = (const float4*)bias;
    for (int rr = 0; rr < 2; ++rr) {
        int r = wv + rr * 4, b = b0 + r;
        float s = 0.f, sq = 0.f;
#pragma unroll
        for (int q = 0; q < 4; ++q) {
            int m4 = lane + 64 * q;
            float4 z4 = b4[m4];
#pragma unroll
            for (int k2 = 0; k2 < 8; ++k2) {
                float4 v = ((const float4*)(P + (size_t)k2 * 32768 + (size_t)b * 1024))[m4];
                z4 = f4add(z4, v);
            }
            int c0 = 4 * m4 - k0;
            if ((unsigned)c0 < 128u) *(float4*)(Atile + r * 128 + c0) = z4;
            s += z4.x + z4.y + z4.z + z4.w;
            sq += z4.x * z4.x + z4.y * z4.y + z4.z * z4.z + z4.w * z4.w;
        }
        wreduce(s, sq);
        if (lane == 0) {
            float mean = s * (1.f / 1024.f);
            stats[r] = mean;
            stats[8 + r] = rsqrtf(sq * (1.f / 1024.f) - mean * mean + LNEPS);
        }
    }
    __syncthreads();
    for (int i = tid; i < 1024; i += 256) {
        int r = i >> 7, c = i & 127, m = k0 + c;
        float xh = (Atile[i] - stats[r]) * stats[8 + r];
        float y = fmaf(xh, g[m], be[m]);
        float sg = 1.f / (1.f + __expf(-y));
        Atile[i] = y * sg;
    }
    __syncthreads();
    nt_inner128v(Atile, W1, k0, n0, Pout, ks, b0);
}

// K3: LN2 recompute + cb partial + mo@Wk^T slice. grid 1024 (dc4 x b32 x mc8)
__global__ __launch_bounds__(256) void k_wpart(const float* __restrict__ P2a, const float* __restrict__ memb1,
                        const float* __restrict__ lng1, const float* __restrict__ lnb1,
                        const float* __restrict__ bk, const float* __restrict__ Wk,
                        float* __restrict__ wpart, float* __restrict__ cbpart) {
    __shared__ float shm[136];
    int bid = blockIdx.x, tid = threadIdx.x;
    int dc = bid & 3, b = (bid >> 2) & 31, mc = bid >> 7, m0 = mc * 128;
    float* red = shm + 128;
    float4 z4 = ((const float4*)memb1)[tid];
#pragma unroll
    for (int k2 = 0; k2 < 8; ++k2) {
        float4 v = ((const float4*)(P2a + (size_t)k2 * 32768 + (size_t)b * 1024))[tid];
        z4 = f4add(z4, v);
    }
    float s = z4.x + z4.y + z4.z + z4.w;
    float sq = z4.x * z4.x + z4.y * z4.y + z4.z * z4.z + z4.w * z4.w;
    int c0 = 4 * tid - m0;
    if ((unsigned)c0 < 128u) *(float4*)(shm + c0) = z4;
    dreduce(s, sq, red);
    float mean = s * (1.f / 1024.f);
    float rstd = rsqrtf(sq * (1.f / 1024.f) - mean * mean + LNEPS);
    if (tid < 128) {
        int m = m0 + tid;
        float xh = (shm[tid] - mean) * rstd;
        float y = fmaf(xh, lng1[m], lnb1[m]);
        float sg = 1.f / (1.f + __expf(-y));
        shm[tid] = y * sg;
    }
    __syncthreads();
    if (dc == 0) {
        float c = (tid < 128) ? bk[m0 + tid] * shm[tid] : 0.f;
        float d2 = 0.f;
        dreduce(c, d2, red);
        if (tid == 0) cbpart[mc * 32 + b] = c;
    }
    t_inner(shm, Wk, dc * 256, m0, wpart + (size_t)(mc * 32 + b) * 1024 + dc * 256);
}

// K4: one pass over X. grid (32,32)
__global__ __launch_bounds__(256) void k_bigpass(const float* __restrict__ X, const float* __restrict__ wpart,
                          const float* __restrict__ wv_row, const float* __restrict__ cbpart,
                          const float* __restrict__ bvsum,
                          float* __restrict__ t_part, float* __restrict__ p_part,
                          float* __restrict__ rs_part) {
    __shared__ float red[4][1024];
    __shared__ float rsum_s[4];
    int b = blockIdx.y, ch = blockIdx.x;
    int wv = threadIdx.x >> 6, lane = threadIdx.x & 63;
    float4 wreg[4], tacc[4], pacc[4];
    const float4* wp4 = (const float4*)wpart;
    const float4* wr4 = (const float4*)wv_row;
#pragma unroll
    for (int j = 0; j < 4; ++j) {
        int d4 = lane + 64 * j;
        float4 a = make_float4(0.f, 0.f, 0.f, 0.f);
#pragma unroll
        for (int mc = 0; mc < 8; ++mc) a = f4add(a, wp4[(size_t)(mc * 32 + b) * 256 + d4]);
        float4 wr = wr4[d4];
        wreg[j].x = 1024.f * a.x - wr.x;
        wreg[j].y = 1024.f * a.y - wr.y;
        wreg[j].z = 1024.f * a.z - wr.z;
        wreg[j].w = 1024.f * a.w - wr.w;
        tacc[j] = make_float4(0.f, 0.f, 0.f, 0.f);
        pacc[j] = make_float4(0.f, 0.f, 0.f, 0.f);
    }
    float cbs = 0.f;
#pragma unroll
    for (int mc = 0; mc < 8; ++mc) cbs += cbpart[mc * 32 + b];
    float cbv = 1024.f * cbs - *bvsum;
    float rloc = 0.f;
    int s0r = ch * 64 + wv * 16;
#pragma unroll 2
    for (int i = 0; i < 16; ++i) {
        const float4* xr = (const float4*)(X + ((size_t)b * Sc + s0r + i) * Dc);
        float4 x[4]; float pp = 0.f;
#pragma unroll
        for (int j = 0; j < 4; ++j) {
            x[j] = xr[lane + 64 * j];
            pp += x[j].x * wreg[j].x + x[j].y * wreg[j].y + x[j].z * wreg[j].z + x[j].w * wreg[j].w;
        }
#pragma unroll
        for (int o = 32; o; o >>= 1) pp += __shfl_xor(pp, o);
        float r = pp + cbv;
        rloc += r;
#pragma unroll
        for (int j = 0; j < 4; ++j) {
            tacc[j].x = fmaf(x[j].x, r, tacc[j].x);
            tacc[j].y = fmaf(x[j].y, r, tacc[j].y);
            tacc[j].z = fmaf(x[j].z, r, tacc[j].z);
            tacc[j].w = fmaf(x[j].w, r, tacc[j].w);
            pacc[j].x += x[j].x; pacc[j].y += x[j].y;
            pacc[j].z += x[j].z; pacc[j].w += x[j].w;
        }
    }
    float4* redv = (float4*)red[wv];
#pragma unroll
    for (int j = 0; j < 4; ++j) redv[lane + 64 * j] = tacc[j];
    if (lane == 0) rsum_s[wv] = rloc;
    __syncthreads();
    size_t pb = ((size_t)b * 32 + ch) * 1024;
    for (int j = 0; j < 4; ++j) {
        int d = threadIdx.x + 256 * j;
        t_part[pb + d] = red[0][d] + red[1][d] + red[2][d] + red[3][d];
    }
    if (threadIdx.x == 0) rs_part[b * 32 + ch] = rsum_s[0] + rsum_s[1] + rsum_s[2] + rsum_s[3];
    __syncthreads();
#pragma unroll
    for (int j = 0; j < 4; ++j) redv[lane + 64 * j] = pacc[j];
    __syncthreads();
    for (int j = 0; j < 4; ++j) {
        int d = threadIdx.x + 256 * j;
        p_part[pb + d] = red[0][d] + red[1][d] + red[2][d] + red[3][d];
    }
}

// K5: 5 GEMMs in one launch; z<3 self-reduce slab from t_part/p_part. grid 2560
__global__ __launch_bounds__(256) void k_gates(const float* __restrict__ t_part, const float* __restrict__ p_part,
                        const float* __restrict__ mem,
                        const float* __restrict__ Wk, const float* __restrict__ Wf,
                        const float* __restrict__ Wu,
                        float* __restrict__ Pg, float* __restrict__ Pfp, float* __restrict__ Pup,
                        float* __restrict__ Pfm, float* __restrict__ Pum) {
    __shared__ float Atile[1024];
    int bid = blockIdx.x, tid = threadIdx.x;
    int z = bid >> 9, t = bid & 511;
    int n0 = (t & 15) * 64, b0 = ((t >> 4) & 3) * 8, ks = t >> 6, k0 = ks * 128;
    if (z >= 3) {
        load_A128(Atile, mem, b0, k0);
        __syncthreads();
        if (z == 3) nt_inner128v(Atile, Wf + (size_t)1024 * 1024, k0, n0, Pfm, ks, b0);
        else        nt_inner128v(Atile, Wu + (size_t)1024 * 1024, k0, n0, Pum, ks, b0);
        return;
    }
    const float* src = (z == 0) ? t_part : p_part;
    float scale = (z == 0) ? 1.f : (1.f / 2048.f);
    {
        int r = tid >> 5, c4 = tid & 31;
        int b = b0 + r;
        const float4* base = (const float4*)(src + (size_t)b * 32 * 1024 + k0) + c4;
        float4 acc = make_float4(0.f, 0.f, 0.f, 0.f);
#pragma unroll 8
        for (int ch = 0; ch < 32; ++ch) acc = f4add(acc, base[(size_t)ch * 256]);
        acc.x *= scale; acc.y *= scale; acc.z *= scale; acc.w *= scale;
        *(float4*)(Atile + r * 128 + 4 * c4) = acc;
    }
    __syncthreads();
    if (z == 0)      nt_inner128v(Atile, Wk, k0, n0, Pg, ks, b0);
    else if (z == 1) nt_inner128v(Atile, Wf, k0, n0, Pfp, ks, b0);
    else             nt_inner128v(Atile, Wu, k0, n0, Pup, ks, b0);
}

// K6/K7: LN-bwd recompute (+rsv self-reduce) + gemm-T slice. grid 1024
__global__ __launch_bounds__(256) void k_lnbwd_gemmT(const float* __restrict__ Pz, const float* __restrict__ bias,
                              const float* __restrict__ g, const float* __restrict__ be,
                              const float* __restrict__ Pgrad, int mode,
                              const float* __restrict__ bk, const float* __restrict__ rs_part,
                              const float* __restrict__ W, float* __restrict__ Pout) {
    __shared__ float shm[392];
    int bid = blockIdx.x, tid = threadIdx.x;
    int dc = bid & 3, b = (bid >> 2) & 31, mc = bid >> 7, m0 = mc * 128;
    float* red = shm + 384;
    float rsb = 0.f;
    if (mode) {
        float v = (tid < 32) ? rs_part[b * 32 + tid] : 0.f, d2 = 0.f;
        dreduce(v, d2, red);
        rsb = v;
    }
    float4 z4 = ((const float4*)bias)[tid];
#pragma unroll
    for (int k2 = 0; k2 < 8; ++k2) {
        float4 v = ((const float4*)(Pz + (size_t)k2 * 32768 + (size_t)b * 1024))[tid];
        z4 = f4add(z4, v);
    }
    float s = z4.x + z4.y + z4.z + z4.w;
    float sq = z4.x * z4.x + z4.y * z4.y + z4.z * z4.z + z4.w * z4.w;
    dreduce(s, sq, red);
    float mean = s * (1.f / 1024.f);
    float rstd = rsqrtf(sq * (1.f / 1024.f) - mean * mean + LNEPS);
    float4 g4 = make_float4(0.f, 0.f, 0.f, 0.f);
#pragma unroll
    for (int k2 = 0; k2 < 8; ++k2) {
        float4 v = ((const float4*)(Pgrad + (size_t)k2 * 32768 + (size_t)b * 1024))[tid];
        g4 = f4add(g4, v);
    }
    if (mode) {
        float4 bk4 = ((const float4*)bk)[tid];
        g4.x = SCv * (g4.x + bk4.x * rsb);
        g4.y = SCv * (g4.y + bk4.y * rsb);
        g4.z = SCv * (g4.z + bk4.z * rsb);
        g4.w = SCv * (g4.w + bk4.w * rsb);
    }
    float4 gg = ((const float4*)g)[tid], bb = ((const float4*)be)[tid];
    float sa = 0.f, sax = 0.f;
    float4 a4, xh4;
    {
        xh4.x = (z4.x - mean) * rstd;
        float y = fmaf(xh4.x, gg.x, bb.x);
        float sg2 = 1.f / (1.f + __expf(-y));
        a4.x = g4.x * (sg2 * (1.f + y * (1.f - sg2))) * gg.x;
        sa += a4.x; sax += a4.x * xh4.x;
        xh4.y = (z4.y - mean) * rstd;
        y = fmaf(xh4.y, gg.y, bb.y);
        sg2 = 1.f / (1.f + __expf(-y));
        a4.y = g4.y * (sg2 * (1.f + y * (1.f - sg2))) * gg.y;
        sa += a4.y; sax += a4.y * xh4.y;
        xh4.z = (z4.z - mean) * rstd;
        y = fmaf(xh4.z, gg.z, bb.z);
        sg2 = 1.f / (1.f + __expf(-y));
        a4.z = g4.z * (sg2 * (1.f + y * (1.f - sg2))) * gg.z;
        sa += a4.z; sax += a4.z * xh4.z;
        xh4.w = (z4.w - mean) * rstd;
        y = fmaf(xh4.w, gg.w, bb.w);
        sg2 = 1.f / (1.f + __expf(-y));
        a4.w = g4.w * (sg2 * (1.f + y * (1.f - sg2))) * gg.w;
        sa += a4.w; sax += a4.w * xh4.w;
    }
    int c0 = 4 * tid - m0;
    if ((unsigned)c0 < 128u) {
        *(float4*)(shm + c0) = a4;
        *(float4*)(shm + 128 + c0) = xh4;
    }
    dreduce(sa, sax, red);
    float ma = sa * (1.f / 1024.f), mx = sax * (1.f / 1024.f);
    if (tid < 128) shm[256 + tid] = rstd * (shm[tid] - ma - shm[128 + tid] * mx);
    __syncthreads();
    t_inner(shm + 256, W, dc * 256, m0, Pout + (size_t)(mc * 32 + b) * 1024 + dc * 256);
}

// K8: gate/update recompute -> nmem tile -> @W0 partials; writes out_nm. grid 512
__global__ __launch_bounds__(256) void k_upd_g3(const float* __restrict__ Pfm, const float* __restrict__ Pfp,
                         const float* __restrict__ Pum, const float* __restrict__ Pup,
                         const float* __restrict__ surp,
                         const float* __restrict__ bf, const float* __restrict__ bu,
                         const float* __restrict__ mem, const float* __restrict__ mom,
                         const float* __restrict__ eta, const float* __restrict__ theta,
                         const float* __restrict__ W0, float* __restrict__ P3a,
                         float* __restrict__ out_nm) {
    __shared__ float Atile[1024];
    int bid = blockIdx.x, tid = threadIdx.x;
    int n0idx = bid & 15, n0 = n0idx * 64, b0 = ((bid >> 4) & 3) * 8, ks = bid >> 6, k0 = ks * 128;
    float etav = eta[0], thv = theta[0];
    int r = tid >> 5, c4 = tid & 31, b = b0 + r;
    int m4 = (k0 >> 2) + c4;
    float4 zf = ((const float4*)bf)[m4];
    float4 zu = ((const float4*)bu)[m4];
    float4 sv = make_float4(0.f, 0.f, 0.f, 0.f);
#pragma unroll
    for (int k2 = 0; k2 < 8; ++k2) {
        size_t ob4 = (size_t)k2 * 8192 + (size_t)b * 256 + m4;
        zf = f4add(zf, f4add(((const float4*)Pfm)[ob4], ((const float4*)Pfp)[ob4]));
        zu = f4add(zu, f4add(((const float4*)Pum)[ob4], ((const float4*)Pup)[ob4]));
        sv = f4add(sv, ((const float4*)surp)[ob4]);
    }
    float4 me = ((const float4*)mem)[(size_t)b * 256 + m4];
    float4 mo = ((const float4*)mom)[(size_t)b * 256 + m4];
    float4 nm;
    {
        float f = 1.f / (1.f + __expf(-zf.x)), u = 1.f / (1.f + __expf(-zu.x));
        nm.x = (1.f - f) * me.x + u * (etav * mo.x + thv * sv.x);
        f = 1.f / (1.f + __expf(-zf.y)); u = 1.f / (1.f + __expf(-zu.y));
        nm.y = (1.f - f) * me.y + u * (etav * mo.y + thv * sv.y);
        f = 1.f / (1.f + __expf(-zf.z)); u = 1.f / (1.f + __expf(-zu.z));
        nm.z = (1.f - f) * me.z + u * (etav * mo.z + thv * sv.z);
        f = 1.f / (1.f + __expf(-zf.w)); u = 1.f / (1.f + __expf(-zu.w));
        nm.w = (1.f - f) * me.w + u * (etav * mo.w + thv * sv.w);
    }
    *(float4*)(Atile + r * 128 + 4 * c4) = nm;
    if (n0idx == 0) ((float4*)out_nm)[(size_t)b * 256 + m4] = nm;
    __syncthreads();
    nt_inner128v(Atile, W0, k0, n0, P3a, ks, b0);
}

// K10: final LN -> out. grid 32
__global__ __launch_bounds__(256) void k_final(const float* __restrict__ P4a, const float* __restrict__ memb1,
                        const float* __restrict__ lng1, const float* __restrict__ lnb1,
                        float* __restrict__ out) {
    __shared__ float sm[8];
    int b = blockIdx.x, tid = threadIdx.x;
    float4 z4 = ((const float4*)memb1)[tid];
#pragma unroll
    for (int k2 = 0; k2 < 8; ++k2) {
        float4 v = ((const float4*)(P4a + (size_t)k2 * 32768 + (size_t)b * 1024))[tid];
        z4 = f4add(z4, v);
    }
    float s = z4.x + z4.y + z4.z + z4.w;
    float sq = z4.x * z4.x + z4.y * z4.y + z4.z * z4.z + z4.w * z4.w;
    dreduce(s, sq, sm);
    float mean = s * (1.f / 1024.f);
    float rstd = rsqrtf(sq * (1.f / 1024.f) - mean * mean + LNEPS);
    float4 gg = ((const float4*)lng1)[tid], bb = ((const float4*)lnb1)[tid];
    float4 o;
    {
        float xh = (z4.x - mean) * rstd, y = fmaf(xh, gg.x, bb.x);
        o.x = y / (1.f + __expf(-y));
        xh = (z4.y - mean) * rstd; y = fmaf(xh, gg.y, bb.y);
        o.y = y / (1.f + __expf(-y));
        xh = (z4.z - mean) * rstd; y = fmaf(xh, gg.z, bb.z);
        o.z = y / (1.f + __expf(-y));
        xh = (z4.w - mean) * rstd; y = fmaf(xh, gg.w, bb.w);
        o.w = y / (1.f + __expf(-y));
    }
    ((float4*)out)[(size_t)b * 256 + tid] = o;
}

extern "C" void kernel_launch(void* const* d_in, const int* in_sizes, int n_in,
                              void* d_out, int out_size, void* d_ws, size_t ws_size,
                              hipStream_t stream) {
    const float* X    = (const float*)d_in[0];
    const float* mem  = (const float*)d_in[1];
    const float* mom  = (const float*)d_in[2];
    const float* Wk   = (const float*)d_in[3];
    const float* bk   = (const float*)d_in[4];
    const float* Wv   = (const float*)d_in[5];
    const float* bv   = (const float*)d_in[6];
    const float* memW = (const float*)d_in[7];
    const float* memb = (const float*)d_in[8];
    const float* lng  = (const float*)d_in[9];
    const float* lnb  = (const float*)d_in[10];
    const float* Wf   = (const float*)d_in[11];
    const float* bf   = (const float*)d_in[12];
    const float* Wu   = (const float*)d_in[15];
    const float* bu   = (const float*)d_in[16];
    const float* eta  = (const float*)d_in[17];
    const float* theta= (const float*)d_in[18];
    float* out = (float*)d_out;

    const size_t BM = (size_t)Bc * Mc;     // 32768
    float* ws = (float*)d_ws;
    float* P1a    = ws;                    // 8*BM each
    float* P2a    = ws + 8 * BM;
    float* wpart  = ws + 16 * BM;
    float* Pg     = ws + 24 * BM;
    float* Pfp    = ws + 32 * BM;
    float* Pup    = ws + 40 * BM;
    float* Pfm    = ws + 48 * BM;
    float* Pum    = ws + 56 * BM;
    float* ghp    = ws + 64 * BM;
    float* surp   = ws + 72 * BM;
    float* P3a    = ws + 80 * BM;
    float* P4a    = ws + 88 * BM;
    float* t_part = ws + 96 * BM;          // 32*BM
    float* p_part = ws + 128 * BM;         // 32*BM
    float* wv_row = ws + 160 * BM;         // 1024
    float* bvsum  = wv_row + 1024;         // 1
    float* cbpart = bvsum + 1;             // 256
    float* rs_part= cbpart + 256;          // 1024

    const float* W0 = memW;
    const float* W1 = memW + (size_t)Mc * Mc;

    k_front<<<768, 256, 0, stream>>>(Wv, bv, mem, W0, wv_row, bvsum, P1a);
    k_gemm_ln<<<512, 256, 0, stream>>>(P1a, memb, lng, lnb, W1, P2a);
    k_wpart<<<1024, 256, 0, stream>>>(P2a, memb + 1024, lng + 1024, lnb + 1024, bk, Wk, wpart, cbpart);
    k_bigpass<<<dim3(32, 32), 256, 0, stream>>>(X, wpart, wv_row, cbpart, bvsum, t_part, p_part, rs_part);
    k_gates<<<2560, 256, 0, stream>>>(t_part, p_part, mem, Wk, Wf, Wu, Pg, Pfp, Pup, Pfm, Pum);
    k_lnbwd_gemmT<<<1024, 256, 0, stream>>>(P2a, memb + 1024, lng + 1024, lnb + 1024, Pg, 1, bk, rs_part, W1, ghp);
    k_lnbwd_gemmT<<<1024, 256, 0, stream>>>(P1a, memb, lng, lnb, ghp, 0, bk, rs_part, W0, surp);
    k_upd_g3<<<512, 256, 0, stream>>>(Pfm, Pfp, Pum, Pup, surp, bf, bu, mem, mom, eta, theta, W0, P3a, out + BM);
    k_gemm_ln<<<512, 256, 0, stream>>>(P3a, memb, lng, lnb, W1, P4a);
    k_final<<<32, 256, 0, stream>>>(P4a, memb + 1024, lng + 1024, lnb + 1024, out);
}

// Round 7
// 162.615 us; speedup vs baseline: 4.9004x; 1.0163x over previous
//
#include <hip/hip_runtime.h>
#include <math.h>

#define Bc 32
#define Sc 2048
#define Dc 1024
#define Mc 1024
#define LNEPS 1e-5f
#define SCv (1.f/67108864.f)   // 1/(B*S*M)

__device__ __forceinline__ float4 f4add(float4 a, float4 b) {
    return make_float4(a.x + b.x, a.y + b.y, a.z + b.z, a.w + b.w);
}

__device__ __forceinline__ void dreduce(float& a, float& b, float* sm) {
#pragma unroll
    for (int o = 32; o; o >>= 1) { a += __shfl_xor(a, o); b += __shfl_xor(b, o); }
    int w = threadIdx.x >> 6;
    if ((threadIdx.x & 63) == 0) { sm[w] = a; sm[4 + w] = b; }
    __syncthreads();
    a = sm[0] + sm[1] + sm[2] + sm[3];
    b = sm[4] + sm[5] + sm[6] + sm[7];
    __syncthreads();
}

__device__ __forceinline__ void wreduce(float& a, float& b) {
#pragma unroll
    for (int o = 32; o; o >>= 1) { a += __shfl_xor(a, o); b += __shfl_xor(b, o); }
}

// XCD swizzles: same W-slice -> same XCD (dispatch assumed round-robin bid%8)
// 512-block NT kernels: slice = (ks,n0i), shared by 4 b0i
__device__ __forceinline__ void nt_map(int t, int& n0i, int& b0i, int& ks) {
    int xcd = t & 7, rest = t >> 3;      // rest in [0,64)
    b0i = rest & 3;
    int q = rest >> 2;                   // [0,16)
    int s = q * 8 + xcd;                 // slice [0,128)
    ks = s >> 4; n0i = s & 15;
}
// 1024-block T kernels: slice = (dc,mc), shared by 32 b
__device__ __forceinline__ void t_map(int t, int& dc, int& b, int& mc) {
    int xcd = t & 7, rest = t >> 3;      // [0,128)
    b = rest & 31;
    int q = rest >> 5;                   // [0,4)
    int s = q * 8 + xcd;                 // [0,32)
    dc = s >> 3; mc = s & 7;
}

// A-tile [8][128] from A[32][1024]
__device__ __forceinline__ void load_A128(float* Atile, const float* A, int b0, int k0) {
    for (int i = threadIdx.x; i < 1024; i += 256) {
        int r = i >> 7, c = i & 127;
        Atile[i] = A[(size_t)(b0 + r) * 1024 + k0 + c];
    }
}

// NT inner: Atile[8][128] x W[k0..+128)[n0..+64) -> P[ks][b][n]; float4 W loads,
// k-groups folded by shfl_xor(16),(32)
__device__ __forceinline__ void nt_inner128v(const float* Atile, const float* W, int k0, int n0,
                                             float* P, int ks, int b0) {
    int lane = threadIdx.x & 63, bl = threadIdx.x >> 6;
    int n4 = lane & 15, kg = lane >> 4;
    const float* a0 = Atile + bl * 128;
    const float* a1 = Atile + (bl + 4) * 128;
    const float4* Wp = (const float4*)(W + (size_t)k0 * 1024 + n0);
    float4 acc0 = make_float4(0.f, 0.f, 0.f, 0.f);
    float4 acc1 = make_float4(0.f, 0.f, 0.f, 0.f);
#pragma unroll 8
    for (int i = 0; i < 32; ++i) {
        int k = i * 4 + kg;
        float4 w4 = Wp[(size_t)k * 256 + n4];
        float av0 = a0[k], av1 = a1[k];
        acc0.x = fmaf(av0, w4.x, acc0.x); acc0.y = fmaf(av0, w4.y, acc0.y);
        acc0.z = fmaf(av0, w4.z, acc0.z); acc0.w = fmaf(av0, w4.w, acc0.w);
        acc1.x = fmaf(av1, w4.x, acc1.x); acc1.y = fmaf(av1, w4.y, acc1.y);
        acc1.z = fmaf(av1, w4.z, acc1.z); acc1.w = fmaf(av1, w4.w, acc1.w);
    }
#pragma unroll
    for (int o = 16; o <= 32; o <<= 1) {
        acc0.x += __shfl_xor(acc0.x, o); acc0.y += __shfl_xor(acc0.y, o);
        acc0.z += __shfl_xor(acc0.z, o); acc0.w += __shfl_xor(acc0.w, o);
        acc1.x += __shfl_xor(acc1.x, o); acc1.y += __shfl_xor(acc1.y, o);
        acc1.z += __shfl_xor(acc1.z, o); acc1.w += __shfl_xor(acc1.w, o);
    }
    if (kg == 0) {
        size_t base = (size_t)ks * 32768 + n0 + 4 * n4;
        *(float4*)&P[base + (size_t)(b0 + bl) * 1024] = acc0;
        *(float4*)&P[base + (size_t)(b0 + bl + 4) * 1024] = acc1;
    }
}

// T inner: out[d]=dot(Asl, W[d][m0..+128)), 256 d per block, coalesced 512B row chunks
__device__ __forceinline__ void t_inner(const float* Asl, const float* W,
                                        int dbase, int m0, float* outp) {
    int lane = threadIdx.x & 63, wv = threadIdx.x >> 6;
    int half = lane >> 5, m4 = lane & 31;
    float4 a4 = ((const float4*)Asl)[m4];
    int d0 = dbase + wv * 64 + half;
    float res = 0.f;
#pragma unroll 8
    for (int p = 0; p < 32; ++p) {
        int d = d0 + p * 2;
        float4 w4 = ((const float4*)(W + (size_t)d * 1024 + m0))[m4];
        float v = w4.x * a4.x + w4.y * a4.y + w4.z * a4.z + w4.w * a4.w;
#pragma unroll
        for (int o = 1; o < 32; o <<= 1) v += __shfl_xor(v, o);
        res = (m4 == p) ? v : res;
    }
    outp[wv * 64 + m4 * 2 + half] = res;
}

// K1: wv_row/bvsum (bid<256) + mem@W0 partials (512, swizzled). grid 768
__global__ __launch_bounds__(256) void k_front(const float* __restrict__ Wv, const float* __restrict__ bv,
                        const float* __restrict__ mem, const float* __restrict__ W0,
                        float* __restrict__ wv_row, float* __restrict__ bvsum,
                        float* __restrict__ P1a) {
    __shared__ float shm[1032];
    int bid = blockIdx.x, tid = threadIdx.x;
    if (bid < 256) {
        float s1 = 0.f, s2 = 0.f, s3 = 0.f, s4 = 0.f;
        for (int m = tid; m < 1024; m += 256) {
            s1 += Wv[(size_t)bid * 1024 + m];
            s2 += Wv[(size_t)(bid + 256) * 1024 + m];
            s3 += Wv[(size_t)(bid + 512) * 1024 + m];
            s4 += Wv[(size_t)(bid + 768) * 1024 + m];
        }
        dreduce(s1, s2, shm + 1024);
        dreduce(s3, s4, shm + 1024);
        if (tid == 0) {
            wv_row[bid] = s1; wv_row[bid + 256] = s2;
            wv_row[bid + 512] = s3; wv_row[bid + 768] = s4;
        }
        if (bid == 0) {
            float v = 0.f, d2 = 0.f;
            for (int m = tid; m < 1024; m += 256) v += bv[m];
            dreduce(v, d2, shm + 1024);
            if (tid == 0) *bvsum = v;
        }
    } else {
        int n0i, b0i, ks;
        nt_map(bid - 256, n0i, b0i, ks);
        int n0 = n0i * 64, b0 = b0i * 8, k0 = ks * 128;
        load_A128(shm, mem, b0, k0);
        __syncthreads();
        nt_inner128v(shm, W0, k0, n0, P1a, ks, b0);
    }
}

// K2/K10: h = SiLU(LN(bias + sum8 P)) tile, then @W1 -> Pout. grid 512 (swizzled)
__global__ __launch_bounds__(256) void k_gemm_ln(const float* __restrict__ P, const float* __restrict__ bias,
                          const float* __restrict__ g, const float* __restrict__ be,
                          const float* __restrict__ W1, float* __restrict__ Pout) {
    __shared__ float shm[1040];
    int tid = threadIdx.x;
    int n0i, b0i, ks;
    nt_map(blockIdx.x, n0i, b0i, ks);
    int n0 = n0i * 64, b0 = b0i * 8, k0 = ks * 128;
    float* Atile = shm; float* stats = shm + 1024;
    int wv = tid >> 6, lane = tid & 63;
    const float4* b4 = (const float4*)bias;
    for (int rr = 0; rr < 2; ++rr) {
        int r = wv + rr * 4, b = b0 + r;
        float s = 0.f, sq = 0.f;
#pragma unroll
        for (int q = 0; q < 4; ++q) {
            int m4 = lane + 64 * q;
            float4 z4 = b4[m4];
#pragma unroll
            for (int k2 = 0; k2 < 8; ++k2) {
                float4 v = ((const float4*)(P + (size_t)k2 * 32768 + (size_t)b * 1024))[m4];
                z4 = f4add(z4, v);
            }
            int c0 = 4 * m4 - k0;
            if ((unsigned)c0 < 128u) *(float4*)(Atile + r * 128 + c0) = z4;
            s += z4.x + z4.y + z4.z + z4.w;
            sq += z4.x * z4.x + z4.y * z4.y + z4.z * z4.z + z4.w * z4.w;
        }
        wreduce(s, sq);
        if (lane == 0) {
            float mean = s * (1.f / 1024.f);
            stats[r] = mean;
            stats[8 + r] = rsqrtf(sq * (1.f / 1024.f) - mean * mean + LNEPS);
        }
    }
    __syncthreads();
    for (int i = tid; i < 1024; i += 256) {
        int r = i >> 7, c = i & 127, m = k0 + c;
        float xh = (Atile[i] - stats[r]) * stats[8 + r];
        float y = fmaf(xh, g[m], be[m]);
        float sg = 1.f / (1.f + __expf(-y));
        Atile[i] = y * sg;
    }
    __syncthreads();
    nt_inner128v(Atile, W1, k0, n0, Pout, ks, b0);
}

// K3: LN2 recompute + cb partial + mo@Wk^T slice. grid 1024 (swizzled T)
__global__ __launch_bounds__(256) void k_wpart(const float* __restrict__ P2a, const float* __restrict__ memb1,
                        const float* __restrict__ lng1, const float* __restrict__ lnb1,
                        const float* __restrict__ bk, const float* __restrict__ Wk,
                        float* __restrict__ wpart, float* __restrict__ cbpart) {
    __shared__ float shm[136];
    int tid = threadIdx.x;
    int dc, b, mc;
    t_map(blockIdx.x, dc, b, mc);
    int m0 = mc * 128;
    float* red = shm + 128;
    float4 z4 = ((const float4*)memb1)[tid];
#pragma unroll
    for (int k2 = 0; k2 < 8; ++k2) {
        float4 v = ((const float4*)(P2a + (size_t)k2 * 32768 + (size_t)b * 1024))[tid];
        z4 = f4add(z4, v);
    }
    float s = z4.x + z4.y + z4.z + z4.w;
    float sq = z4.x * z4.x + z4.y * z4.y + z4.z * z4.z + z4.w * z4.w;
    int c0 = 4 * tid - m0;
    if ((unsigned)c0 < 128u) *(float4*)(shm + c0) = z4;
    dreduce(s, sq, red);
    float mean = s * (1.f / 1024.f);
    float rstd = rsqrtf(sq * (1.f / 1024.f) - mean * mean + LNEPS);
    if (tid < 128) {
        int m = m0 + tid;
        float xh = (shm[tid] - mean) * rstd;
        float y = fmaf(xh, lng1[m], lnb1[m]);
        float sg = 1.f / (1.f + __expf(-y));
        shm[tid] = y * sg;
    }
    __syncthreads();
    if (dc == 0) {
        float c = (tid < 128) ? bk[m0 + tid] * shm[tid] : 0.f;
        float d2 = 0.f;
        dreduce(c, d2, red);
        if (tid == 0) cbpart[mc * 32 + b] = c;
    }
    t_inner(shm, Wk, dc * 256, m0, wpart + (size_t)(mc * 32 + b) * 1024 + dc * 256);
}

// K4: one pass over X. grid (32,32)
__global__ __launch_bounds__(256) void k_bigpass(const float* __restrict__ X, const float* __restrict__ wpart,
                          const float* __restrict__ wv_row, const float* __restrict__ cbpart,
                          const float* __restrict__ bvsum,
                          float* __restrict__ t_part, float* __restrict__ p_part,
                          float* __restrict__ rs_part) {
    __shared__ float red[4][1024];
    __shared__ float rsum_s[4];
    int b = blockIdx.y, ch = blockIdx.x;
    int wv = threadIdx.x >> 6, lane = threadIdx.x & 63;
    float4 wreg[4], tacc[4], pacc[4];
    const float4* wp4 = (const float4*)wpart;
    const float4* wr4 = (const float4*)wv_row;
#pragma unroll
    for (int j = 0; j < 4; ++j) {
        int d4 = lane + 64 * j;
        float4 a = make_float4(0.f, 0.f, 0.f, 0.f);
#pragma unroll
        for (int mc = 0; mc < 8; ++mc) a = f4add(a, wp4[(size_t)(mc * 32 + b) * 256 + d4]);
        float4 wr = wr4[d4];
        wreg[j].x = 1024.f * a.x - wr.x;
        wreg[j].y = 1024.f * a.y - wr.y;
        wreg[j].z = 1024.f * a.z - wr.z;
        wreg[j].w = 1024.f * a.w - wr.w;
        tacc[j] = make_float4(0.f, 0.f, 0.f, 0.f);
        pacc[j] = make_float4(0.f, 0.f, 0.f, 0.f);
    }
    float cbs = 0.f;
#pragma unroll
    for (int mc = 0; mc < 8; ++mc) cbs += cbpart[mc * 32 + b];
    float cbv = 1024.f * cbs - *bvsum;
    float rloc = 0.f;
    int s0r = ch * 64 + wv * 16;
#pragma unroll 2
    for (int i = 0; i < 16; ++i) {
        const float4* xr = (const float4*)(X + ((size_t)b * Sc + s0r + i) * Dc);
        float4 x[4]; float pp = 0.f;
#pragma unroll
        for (int j = 0; j < 4; ++j) {
            x[j] = xr[lane + 64 * j];
            pp += x[j].x * wreg[j].x + x[j].y * wreg[j].y + x[j].z * wreg[j].z + x[j].w * wreg[j].w;
        }
#pragma unroll
        for (int o = 32; o; o >>= 1) pp += __shfl_xor(pp, o);
        float r = pp + cbv;
        rloc += r;
#pragma unroll
        for (int j = 0; j < 4; ++j) {
            tacc[j].x = fmaf(x[j].x, r, tacc[j].x);
            tacc[j].y = fmaf(x[j].y, r, tacc[j].y);
            tacc[j].z = fmaf(x[j].z, r, tacc[j].z);
            tacc[j].w = fmaf(x[j].w, r, tacc[j].w);
            pacc[j].x += x[j].x; pacc[j].y += x[j].y;
            pacc[j].z += x[j].z; pacc[j].w += x[j].w;
        }
    }
    float4* redv = (float4*)red[wv];
#pragma unroll
    for (int j = 0; j < 4; ++j) redv[lane + 64 * j] = tacc[j];
    if (lane == 0) rsum_s[wv] = rloc;
    __syncthreads();
    size_t pb = ((size_t)b * 32 + ch) * 1024;
    for (int j = 0; j < 4; ++j) {
        int d = threadIdx.x + 256 * j;
        t_part[pb + d] = red[0][d] + red[1][d] + red[2][d] + red[3][d];
    }
    if (threadIdx.x == 0) rs_part[b * 32 + ch] = rsum_s[0] + rsum_s[1] + rsum_s[2] + rsum_s[3];
    __syncthreads();
#pragma unroll
    for (int j = 0; j < 4; ++j) redv[lane + 64 * j] = pacc[j];
    __syncthreads();
    for (int j = 0; j < 4; ++j) {
        int d = threadIdx.x + 256 * j;
        p_part[pb + d] = red[0][d] + red[1][d] + red[2][d] + red[3][d];
    }
}

// K5: chunk reduce -> tbuf, pooled(scaled), rsv. grid 32
__global__ __launch_bounds__(256) void k_reduce(const float* __restrict__ t_part, const float* __restrict__ p_part,
                         const float* __restrict__ rs_part,
                         float* __restrict__ tbuf, float* __restrict__ pooled,
                         float* __restrict__ rsv) {
    int idx = blockIdx.x * 256 + threadIdx.x;      // [0, 8192) float4 slots
    int b = idx >> 8, d4 = idx & 255;
    const float4* tp = (const float4*)t_part + (size_t)b * 8192 + d4;
    const float4* pp = (const float4*)p_part + (size_t)b * 8192 + d4;
    float4 st = make_float4(0.f, 0.f, 0.f, 0.f);
    float4 sp = make_float4(0.f, 0.f, 0.f, 0.f);
#pragma unroll 8
    for (int ch = 0; ch < 32; ++ch) {
        st = f4add(st, tp[(size_t)ch * 256]);
        sp = f4add(sp, pp[(size_t)ch * 256]);
    }
    ((float4*)tbuf)[idx] = st;
    sp.x *= (1.f / 2048.f); sp.y *= (1.f / 2048.f);
    sp.z *= (1.f / 2048.f); sp.w *= (1.f / 2048.f);
    ((float4*)pooled)[idx] = sp;
    if (blockIdx.x == 0 && threadIdx.x < 32) {
        float s = 0.f;
        for (int ch = 0; ch < 32; ++ch) s += rs_part[threadIdx.x * 32 + ch];
        rsv[threadIdx.x] = s;
    }
}

// K6: 5 GEMMs in one launch (all load+NT now). grid 2560 (swizzled per z)
__global__ __launch_bounds__(256) void k_gates(const float* __restrict__ tbuf, const float* __restrict__ pooled,
                        const float* __restrict__ mem,
                        const float* __restrict__ Wk, const float* __restrict__ Wf,
                        const float* __restrict__ Wu,
                        float* __restrict__ Pg, float* __restrict__ Pfp, float* __restrict__ Pup,
                        float* __restrict__ Pfm, float* __restrict__ Pum) {
    __shared__ float Atile[1024];
    int bid = blockIdx.x;
    int z = bid >> 9;
    int n0i, b0i, ks;
    nt_map(bid & 511, n0i, b0i, ks);
    int n0 = n0i * 64, b0 = b0i * 8, k0 = ks * 128;
    const float* A; const float* W; float* P;
    if (z == 0)      { A = tbuf;   W = Wk;                          P = Pg; }
    else if (z == 1) { A = pooled; W = Wf;                          P = Pfp; }
    else if (z == 2) { A = pooled; W = Wu;                          P = Pup; }
    else if (z == 3) { A = mem;    W = Wf + (size_t)1024 * 1024;    P = Pfm; }
    else             { A = mem;    W = Wu + (size_t)1024 * 1024;    P = Pum; }
    load_A128(Atile, A, b0, k0);
    __syncthreads();
    nt_inner128v(Atile, W, k0, n0, P, ks, b0);
}

// K7/K8: LN-bwd recompute + gemm-T slice. grid 1024 (swizzled T; rsv direct)
__global__ __launch_bounds__(256) void k_lnbwd_gemmT(const float* __restrict__ Pz, const float* __restrict__ bias,
                              const float* __restrict__ g, const float* __restrict__ be,
                              const float* __restrict__ Pgrad, int mode,
                              const float* __restrict__ bk, const float* __restrict__ rsv,
                              const float* __restrict__ W, float* __restrict__ Pout) {
    __shared__ float shm[392];
    int tid = threadIdx.x;
    int dc, b, mc;
    t_map(blockIdx.x, dc, b, mc);
    int m0 = mc * 128;
    float* red = shm + 384;
    float rsb = mode ? rsv[b] : 0.f;
    float4 z4 = ((const float4*)bias)[tid];
#pragma unroll
    for (int k2 = 0; k2 < 8; ++k2) {
        float4 v = ((const float4*)(Pz + (size_t)k2 * 32768 + (size_t)b * 1024))[tid];
        z4 = f4add(z4, v);
    }
    float s = z4.x + z4.y + z4.z + z4.w;
    float sq = z4.x * z4.x + z4.y * z4.y + z4.z * z4.z + z4.w * z4.w;
    dreduce(s, sq, red);
    float mean = s * (1.f / 1024.f);
    float rstd = rsqrtf(sq * (1.f / 1024.f) - mean * mean + LNEPS);
    float4 g4 = make_float4(0.f, 0.f, 0.f, 0.f);
#pragma unroll
    for (int k2 = 0; k2 < 8; ++k2) {
        float4 v = ((const float4*)(Pgrad + (size_t)k2 * 32768 + (size_t)b * 1024))[tid];
        g4 = f4add(g4, v);
    }
    if (mode) {
        float4 bk4 = ((const float4*)bk)[tid];
        g4.x = SCv * (g4.x + bk4.x * rsb);
        g4.y = SCv * (g4.y + bk4.y * rsb);
        g4.z = SCv * (g4.z + bk4.z * rsb);
        g4.w = SCv * (g4.w + bk4.w * rsb);
    }
    float4 gg = ((const float4*)g)[tid], bb = ((const float4*)be)[tid];
    float sa = 0.f, sax = 0.f;
    float4 a4, xh4;
    {
        xh4.x = (z4.x - mean) * rstd;
        float y = fmaf(xh4.x, gg.x, bb.x);
        float sg2 = 1.f / (1.f + __expf(-y));
        a4.x = g4.x * (sg2 * (1.f + y * (1.f - sg2))) * gg.x;
        sa += a4.x; sax += a4.x * xh4.x;
        xh4.y = (z4.y - mean) * rstd;
        y = fmaf(xh4.y, gg.y, bb.y);
        sg2 = 1.f / (1.f + __expf(-y));
        a4.y = g4.y * (sg2 * (1.f + y * (1.f - sg2))) * gg.y;
        sa += a4.y; sax += a4.y * xh4.y;
        xh4.z = (z4.z - mean) * rstd;
        y = fmaf(xh4.z, gg.z, bb.z);
        sg2 = 1.f / (1.f + __expf(-y));
        a4.z = g4.z * (sg2 * (1.f + y * (1.f - sg2))) * gg.z;
        sa += a4.z; sax += a4.z * xh4.z;
        xh4.w = (z4.w - mean) * rstd;
        y = fmaf(xh4.w, gg.w, bb.w);
        sg2 = 1.f / (1.f + __expf(-y));
        a4.w = g4.w * (sg2 * (1.f + y * (1.f - sg2))) * gg.w;
        sa += a4.w; sax += a4.w * xh4.w;
    }
    int c0 = 4 * tid - m0;
    if ((unsigned)c0 < 128u) {
        *(float4*)(shm + c0) = a4;
        *(float4*)(shm + 128 + c0) = xh4;
    }
    dreduce(sa, sax, red);
    float ma = sa * (1.f / 1024.f), mx = sax * (1.f / 1024.f);
    if (tid < 128) shm[256 + tid] = rstd * (shm[tid] - ma - shm[128 + tid] * mx);
    __syncthreads();
    t_inner(shm + 256, W, dc * 256, m0, Pout + (size_t)(mc * 32 + b) * 1024 + dc * 256);
}

// K9: gate/update recompute -> nmem tile -> @W0 partials; writes out_nm. grid 512 (swizzled)
__global__ __launch_bounds__(256) void k_upd_g3(const float* __restrict__ Pfm, const float* __restrict__ Pfp,
                         const float* __restrict__ Pum, const float* __restrict__ Pup,
                         const float* __restrict__ surp,
                         const float* __restrict__ bf, const float* __restrict__ bu,
                         const float* __restrict__ mem, const float* __restrict__ mom,
                         const float* __restrict__ eta, const float* __restrict__ theta,
                         const float* __restrict__ W0, float* __restrict__ P3a,
                         float* __restrict__ out_nm) {
    __shared__ float Atile[1024];
    int tid = threadIdx.x;
    int n0i, b0i, ks;
    nt_map(blockIdx.x, n0i, b0i, ks);
    int n0 = n0i * 64, b0 = b0i * 8, k0 = ks * 128;
    float etav = eta[0], thv = theta[0];
    int r = tid >> 5, c4 = tid & 31, b = b0 + r;
    int m4 = (k0 >> 2) + c4;
    float4 zf = ((const float4*)bf)[m4];
    float4 zu = ((const float4*)bu)[m4];
    float4 sv = make_float4(0.f, 0.f, 0.f, 0.f);
#pragma unroll
    for (int k2 = 0; k2 < 8; ++k2) {
        size_t ob4 = (size_t)k2 * 8192 + (size_t)b * 256 + m4;
        zf = f4add(zf, f4add(((const float4*)Pfm)[ob4], ((const float4*)Pfp)[ob4]));
        zu = f4add(zu, f4add(((const float4*)Pum)[ob4], ((const float4*)Pup)[ob4]));
        sv = f4add(sv, ((const float4*)surp)[ob4]);
    }
    float4 me = ((const float4*)mem)[(size_t)b * 256 + m4];
    float4 mo = ((const float4*)mom)[(size_t)b * 256 + m4];
    float4 nm;
    {
        float f = 1.f / (1.f + __expf(-zf.x)), u = 1.f / (1.f + __expf(-zu.x));
        nm.x = (1.f - f) * me.x + u * (etav * mo.x + thv * sv.x);
        f = 1.f / (1.f + __expf(-zf.y)); u = 1.f / (1.f + __expf(-zu.y));
        nm.y = (1.f - f) * me.y + u * (etav * mo.y + thv * sv.y);
        f = 1.f / (1.f + __expf(-zf.z)); u = 1.f / (1.f + __expf(-zu.z));
        nm.z = (1.f - f) * me.z + u * (etav * mo.z + thv * sv.z);
        f = 1.f / (1.f + __expf(-zf.w)); u = 1.f / (1.f + __expf(-zu.w));
        nm.w = (1.f - f) * me.w + u * (etav * mo.w + thv * sv.w);
    }
    *(float4*)(Atile + r * 128 + 4 * c4) = nm;
    if (n0i == 0) ((float4*)out_nm)[(size_t)b * 256 + m4] = nm;
    __syncthreads();
    nt_inner128v(Atile, W0, k0, n0, P3a, ks, b0);
}

// K11: final LN -> out. grid 32
__global__ __launch_bounds__(256) void k_final(const float* __restrict__ P4a, const float* __restrict__ memb1,
                        const float* __restrict__ lng1, const float* __restrict__ lnb1,
                        float* __restrict__ out) {
    __shared__ float sm[8];
    int b = blockIdx.x, tid = threadIdx.x;
    float4 z4 = ((const float4*)memb1)[tid];
#pragma unroll
    for (int k2 = 0; k2 < 8; ++k2) {
        float4 v = ((const float4*)(P4a + (size_t)k2 * 32768 + (size_t)b * 1024))[tid];
        z4 = f4add(z4, v);
    }
    float s = z4.x + z4.y + z4.z + z4.w;
    float sq = z4.x * z4.x + z4.y * z4.y + z4.z * z4.z + z4.w * z4.w;
    dreduce(s, sq, sm);
    float mean = s * (1.f / 1024.f);
    float rstd = rsqrtf(sq * (1.f / 1024.f) - mean * mean + LNEPS);
    float4 gg = ((const float4*)lng1)[tid], bb = ((const float4*)lnb1)[tid];
    float4 o;
    {
        float xh = (z4.x - mean) * rstd, y = fmaf(xh, gg.x, bb.x);
        o.x = y / (1.f + __expf(-y));
        xh = (z4.y - mean) * rstd; y = fmaf(xh, gg.y, bb.y);
        o.y = y / (1.f + __expf(-y));
        xh = (z4.z - mean) * rstd; y = fmaf(xh, gg.z, bb.z);
        o.z = y / (1.f + __expf(-y));
        xh = (z4.w - mean) * rstd; y = fmaf(xh, gg.w, bb.w);
        o.w = y / (1.f + __expf(-y));
    }
    ((float4*)out)[(size_t)b * 256 + tid] = o;
}

extern "C" void kernel_launch(void* const* d_in, const int* in_sizes, int n_in,
                              void* d_out, int out_size, void* d_ws, size_t ws_size,
                              hipStream_t stream) {
    const float* X    = (const float*)d_in[0];
    const float* mem  = (const float*)d_in[1];
    const float* mom  = (const float*)d_in[2];
    const float* Wk   = (const float*)d_in[3];
    const float* bk   = (const float*)d_in[4];
    const float* Wv   = (const float*)d_in[5];
    const float* bv   = (const float*)d_in[6];
    const float* memW = (const float*)d_in[7];
    const float* memb = (const float*)d_in[8];
    const float* lng  = (const float*)d_in[9];
    const float* lnb  = (const float*)d_in[10];
    const float* Wf   = (const float*)d_in[11];
    const float* bf   = (const float*)d_in[12];
    const float* Wu   = (const float*)d_in[15];
    const float* bu   = (const float*)d_in[16];
    const float* eta  = (const float*)d_in[17];
    const float* theta= (const float*)d_in[18];
    float* out = (float*)d_out;

    const size_t BM = (size_t)Bc * Mc;     // 32768
    float* ws = (float*)d_ws;
    float* P1a    = ws;                    // 8*BM each
    float* P2a    = ws + 8 * BM;
    float* wpart  = ws + 16 * BM;
    float* Pg     = ws + 24 * BM;
    float* Pfp    = ws + 32 * BM;
    float* Pup    = ws + 40 * BM;
    float* Pfm    = ws + 48 * BM;
    float* Pum    = ws + 56 * BM;
    float* ghp    = ws + 64 * BM;
    float* surp   = ws + 72 * BM;
    float* P3a    = ws + 80 * BM;
    float* P4a    = ws + 88 * BM;
    float* t_part = ws + 96 * BM;          // 32*BM
    float* p_part = ws + 128 * BM;         // 32*BM
    float* tbuf   = ws + 160 * BM;         // BM
    float* pooled = ws + 161 * BM;         // BM
    float* wv_row = ws + 162 * BM;         // 1024
    float* bvsum  = wv_row + 1024;         // 1
    float* cbpart = bvsum + 1;             // 256
    float* rs_part= cbpart + 256;          // 1024
    float* rsv    = rs_part + 1024;        // 32

    const float* W0 = memW;
    const float* W1 = memW + (size_t)Mc * Mc;

    k_front<<<768, 256, 0, stream>>>(Wv, bv, mem, W0, wv_row, bvsum, P1a);
    k_gemm_ln<<<512, 256, 0, stream>>>(P1a, memb, lng, lnb, W1, P2a);
    k_wpart<<<1024, 256, 0, stream>>>(P2a, memb + 1024, lng + 1024, lnb + 1024, bk, Wk, wpart, cbpart);
    k_bigpass<<<dim3(32, 32), 256, 0, stream>>>(X, wpart, wv_row, cbpart, bvsum, t_part, p_part, rs_part);
    k_reduce<<<32, 256, 0, stream>>>(t_part, p_part, rs_part, tbuf, pooled, rsv);
    k_gates<<<2560, 256, 0, stream>>>(tbuf, pooled, mem, Wk, Wf, Wu, Pg, Pfp, Pup, Pfm, Pum);
    k_lnbwd_gemmT<<<1024, 256, 0, stream>>>(P2a, memb + 1024, lng + 1024, lnb + 1024, Pg, 1, bk, rsv, W1, ghp);
    k_lnbwd_gemmT<<<1024, 256, 0, stream>>>(P1a, memb, lng, lnb, ghp, 0, bk, rsv, W0, surp);
    k_upd_g3<<<512, 256, 0, stream>>>(Pfm, Pfp, Pum, Pup, surp, bf, bu, mem, mom, eta, theta, W0, P3a, out + BM);
    k_gemm_ln<<<512, 256, 0, stream>>>(P3a, memb, lng, lnb, W1, P4a);
    k_final<<<32, 256, 0, stream>>>(P4a, memb + 1024, lng + 1024, lnb + 1024, out);
}